// Round 9
// baseline (2278.432 us; speedup 1.0000x reference)
//
#include <hip/hip_runtime.h>
#include <stdint.h>

typedef unsigned long long u64;

#define NB 8
#define NPTS 4096
#define NC 64
#define KOUT 16
#define TSEL 48          // preselect size (top-48 contains true top-32; gap analysis 100x margin)
#define CHUNK 64         // candidate rows per staged chunk (16 KB fp32 tile)
#define NCHUNK (NPTS / CHUNK)
#define IDXBITS 0xFFFu   // low 12 bits hold candidate index (NPTS = 4096)
#define KEYMASK 0xFFFFF000u

typedef const void __attribute__((address_space(1))) cvg_t;
typedef void __attribute__((address_space(3))) vl_t;

// async 16B global->LDS; both sides linear: LDS dest = wave-uniform base +
// lane*16, global source = wave-uniform base + lane*16 (m97-proven pattern)
static __device__ __forceinline__ void async16(const float* g, float* l) {
    __builtin_amdgcn_global_load_lds((cvg_t*)g, (vl_t*)l, 16, 0, 0);
}

// Issue one chunk's 16 KB of candidate rows into buf (linear, coalesced).
static __device__ __forceinline__ void issue_chunk(const float* __restrict__ pbase,
                                                   float* buf, int tid) {
    const int base = (tid >> 6) * 1024 + (tid & 63) * 4;   // float idx within tile
#pragma unroll
    for (int j = 0; j < 4; ++j)
        async16(pbase + base + j * 256, buf + base + j * 256);
}

// sq[p]: 8 accumulator chains over stride-8 (numpy pairwise-8 == XLA W8 reduce
// chains), separate mul/add roundings, combined ((r0+r1)+(r2+r3))+((r4+r5)+(r6+r7)).
__global__ __launch_bounds__(256) void sq_kernel(const float* __restrict__ pts,
                                                 float* __restrict__ sqw) {
    int p = blockIdx.x * 256 + threadIdx.x;
    const float* r = pts + (size_t)p * NC;
    float acc[8];
#pragma unroll
    for (int j = 0; j < 8; ++j) acc[j] = __fmul_rn(r[j], r[j]);
#pragma unroll
    for (int i = 8; i < 64; i += 8)
#pragma unroll
        for (int j = 0; j < 8; ++j)
            acc[j] = __fadd_rn(acc[j], __fmul_rn(r[i + j], r[i + j]));
    float s01 = __fadd_rn(acc[0], acc[1]);
    float s23 = __fadd_rn(acc[2], acc[3]);
    float s45 = __fadd_rn(acc[4], acc[5]);
    float s67 = __fadd_rn(acc[6], acc[7]);
    sqw[p] = __fadd_rn(__fadd_rn(s01, s23), __fadd_rn(s45, s67));
}

// Maintain an ascending sorted 64-list, one u32 per lane:
// (fp32 key bits truncated to 20 | 12-bit idx). Key >= 0 so uint order == key
// order; truncation err 2.4e-4 rel vs rank-32->48 gap ~2.9 => superset safe.
// Threshold = lane 47 (48th smallest). Wave-parallel shift insert.
__device__ __forceinline__ void stream_insert(uint32_t& list, uint32_t cand, int lane) {
    uint32_t thr = (uint32_t)__builtin_amdgcn_readlane((int)list, 47);
    u64 mask = __ballot(cand < thr);
    while (mask) {
        int src = __ffsll((long long)mask) - 1;
        uint32_t v = (uint32_t)__builtin_amdgcn_readlane((int)cand, src);  // uniform src
        int pos = __popcll(__ballot(list < v));
        uint32_t up = __shfl_up(list, 1);
        list = (lane < pos) ? list : ((lane == pos) ? v : up);
        mask &= (mask - 1);
    }
}

// Re-rank the 48 preselected candidates by the emulated reference key:
// key = fl(fl(sq_n - fl(2*inner)) + sq_m), inner = ONE sequential FMA chain
// over k = 0..63 ascending (XLA:CPU dot_general / Eigen gebp order).
// Streamed x/y loads keep register pressure under the 4-wave cap.
__device__ __forceinline__ void epilogue(uint32_t list, int n, int b, int lane,
                                         const float* __restrict__ pb,
                                         const float* __restrict__ sqb,
                                         float sqn,
                                         const float* __restrict__ xyz,
                                         float* __restrict__ out) {
    int m = (int)(list & IDXBITS);        // every lane holds a real index after chunk 0
    const float4* xr = (const float4*)(pb + (size_t)n * NC);
    const float4* yr = (const float4*)(pb + (size_t)m * NC);
    float acc = 0.f;
#pragma unroll
    for (int i = 0; i < 16; ++i) {
        float4 xv = xr[i];
        float4 yv = yr[i];
        acc = __fmaf_rn(xv.x, yv.x, acc);
        acc = __fmaf_rn(xv.y, yv.y, acc);
        acc = __fmaf_rn(xv.z, yv.z, acc);
        acc = __fmaf_rn(xv.w, yv.w, acc);
    }
    float key = __fadd_rn(__fsub_rn(sqn, __fmul_rn(2.0f, acc)), sqb[m]);

    int rank = 0;
    uint32_t kb = __float_as_uint(key);
#pragma unroll 1
    for (int j = 0; j < TSEL; ++j) {
        float kj = __uint_as_float(
            (uint32_t)__builtin_amdgcn_readlane((int)kb, j));
        int mj = __builtin_amdgcn_readlane(m, j);
        bool less = (kj < key) || (kj == key && mj < m);   // stable: lower idx first
        rank += less ? 1 : 0;
    }
    if (lane < TSEL && rank < 2 * KOUT && (rank & 1) == 0) {  // dilation D=2: even ranks
        int k = rank >> 1;
        const float* xn = xyz + ((size_t)b * NPTS + n) * 3;
        const float* xm = xyz + ((size_t)b * NPTS + m) * 3;
        float xnx = xn[0], xny = xn[1], xnz = xn[2];
        float ox = xm[0], oy = xm[1], oz = xm[2];
        float rx = xnx - ox, ry = xny - oy, rz = xnz - oz;
        float dis = sqrtf(rx * rx + ry * ry + rz * rz);
        float* o = out + (((size_t)b * NPTS + n) * KOUT + k) * 10;
        o[0] = dis; o[1] = rx; o[2] = ry; o[3] = rz;
        o[4] = xnx; o[5] = xny; o[6] = xnz;
        o[7] = ox;  o[8] = oy;  o[9] = oz;
    }
}

// 4 waves/SIMD tier (VGPR cap 64); LDS 34.8 KB -> 4 blocks/CU -> ~46% occupancy.
__global__ __launch_bounds__(256, 4) void knn_kernel(
    const float* __restrict__ xyz,
    const float* __restrict__ pts,
    const float* __restrict__ sqw,
    float* __restrict__ out) {

    __shared__ __align__(16) float ylds[2][CHUNK * NC];   // 2 x 16 KB, dbuf, linear
    __shared__ __align__(16) float xlds[8 * NC];          // 2 KB query tile

    const int tid = threadIdx.x;
    const int lane = tid & 63;
    const int wave = tid >> 6;
    const int b = blockIdx.x >> 9;                  // 512 blocks per batch
    const int rowbase = (blockIdx.x & 511) << 3;    // 8 rows per block
    const int n0 = rowbase + wave * 2;
    const int n1 = n0 + 1;
    const float* pb = pts + (size_t)b * NPTS * NC;
    const float* sqb = sqw + (size_t)b * NPTS;

    // stage the block's 8 query rows into LDS
#pragma unroll
    for (int j = 0; j < 2; ++j) {
        int idx = tid + 256 * j;
        int row = idx >> 6;
        int col = idx & 63;
        xlds[row * NC + col] = pb[(size_t)(rowbase + row) * NC + col];
    }

    const float sqn0 = sqb[n0];
    const float sqn1 = sqb[n1];

    uint32_t list0 = 0xFFFFFFFFu, list1 = 0xFFFFFFFFu;

    issue_chunk(pb, ylds[0], tid);        // async-stage chunk 0
    __syncthreads();                      // vmcnt(0) drain: chunk 0 + x-tile ready

    // per-lane column rotation (bytes): within each 16-lane LDS phase all 16
    // 16B slots are distinct -> zero bank aliasing on y; x cols broadcast-merge
    const int rotb = (lane & 15) << 4;
    const char* xb = (const char*)&xlds[(wave * 2) * NC];   // rows n0 (,+256B: n1)

    for (int c = 0; c < NCHUNK; ++c) {
        const int cb = c & 1;
        if (c + 1 < NCHUNK)               // async-stage next chunk into other buffer
            issue_chunk(pb + (size_t)(c + 1) * (CHUNK * NC), ylds[cb ^ 1], tid);
        {
            const int m = c * CHUNK + lane;
            float sqm = sqb[m];           // hoisted: hides under ds_reads
            const char* yb = (const char*)&ylds[cb][lane * NC];
            float a0x = 0.f, a0y = 0.f, a0z = 0.f, a0w = 0.f;
            float a1x = 0.f, a1y = 0.f, a1z = 0.f, a1w = 0.f;
#pragma unroll
            for (int i = 0; i < 16; ++i) {
                const int colb = ((i << 4) + rotb) & 255;    // rotate, wrap in-row
                float4 y  = *(const float4*)(yb + colb);
                float4 x0 = *(const float4*)(xb + colb);
                float4 x1 = *(const float4*)(xb + 256 + colb);  // imm offset row
                a0x = fmaf(x0.x, y.x, a0x);
                a0y = fmaf(x0.y, y.y, a0y);
                a0z = fmaf(x0.z, y.z, a0z);
                a0w = fmaf(x0.w, y.w, a0w);
                a1x = fmaf(x1.x, y.x, a1x);
                a1y = fmaf(x1.y, y.y, a1y);
                a1z = fmaf(x1.z, y.z, a1z);
                a1w = fmaf(x1.w, y.w, a1w);
            }
            float ip0 = (a0x + a0y) + (a0z + a0w);
            float ip1 = (a1x + a1y) + (a1z + a1w);
            // preselect key: ~1e-4 fp error + 2.4e-4 truncation vs margin ~2.9;
            // final ranking is the epilogue's exact emulated key
            float t0 = fmaxf(fmaf(-2.f, ip0, sqn0 + sqm), 0.f);
            float t1 = fmaxf(fmaf(-2.f, ip1, sqn1 + sqm), 0.f);
            uint32_t c0 = (__float_as_uint(t0) & KEYMASK) | (unsigned)m;
            uint32_t c1 = (__float_as_uint(t1) & KEYMASK) | (unsigned)m;
            stream_insert(list0, c0, lane);
            stream_insert(list1, c1, lane);
        }
        // one barrier per chunk: compiler's vmcnt(0)+lgkmcnt(0) drain before
        // s_barrier guarantees next chunk staged AND this buffer consumed
        __syncthreads();
    }

    epilogue(list0, n0, b, lane, pb, sqb, sqn0, xyz, out);
    epilogue(list1, n1, b, lane, pb, sqb, sqn1, xyz, out);
}

extern "C" void kernel_launch(void* const* d_in, const int* in_sizes, int n_in,
                              void* d_out, int out_size, void* d_ws, size_t ws_size,
                              hipStream_t stream) {
    const float* xyz = (const float*)d_in[0];   // [8,4096,3]
    const float* pts = (const float*)d_in[1];   // [8,4096,64]
    float* sqw = (float*)d_ws;                  // 32768 floats = 128 KB scratch
    float* out = (float*)d_out;                 // [8,4096,16,10]

    sq_kernel<<<(NB * NPTS) / 256, 256, 0, stream>>>(pts, sqw);
    knn_kernel<<<(NB * NPTS) / 8, 256, 0, stream>>>(xyz, pts, sqw, out);
}

// Round 10
// 1226.852 us; speedup vs baseline: 1.8571x; 1.8571x over previous
//
#include <hip/hip_runtime.h>
#include <stdint.h>

typedef unsigned long long u64;

#define NB 8
#define NPTS 4096
#define NC 64
#define KOUT 16
#define TSEL 48          // preselect size (top-48 contains true top-32; gap analysis 100x margin)
#define CHUNK 64         // candidate rows per staged chunk
#define PADROW 68        // floats per staged row: 64 + 4 pad -> 0 conflicts (r2/r6 measured)
#define NCHUNK (NPTS / CHUNK)
#define IDXBITS 0xFFFu   // low 12 bits hold candidate index (NPTS = 4096)
#define KEYMASK 0xFFFFF000u

// sq[p]: 8 accumulator chains over stride-8 (numpy pairwise-8 == XLA W8 reduce
// chains), separate mul/add roundings, combined ((r0+r1)+(r2+r3))+((r4+r5)+(r6+r7)).
__global__ __launch_bounds__(256) void sq_kernel(const float* __restrict__ pts,
                                                 float* __restrict__ sqw) {
    int p = blockIdx.x * 256 + threadIdx.x;
    const float* r = pts + (size_t)p * NC;
    float acc[8];
#pragma unroll
    for (int j = 0; j < 8; ++j) acc[j] = __fmul_rn(r[j], r[j]);
#pragma unroll
    for (int i = 8; i < 64; i += 8)
#pragma unroll
        for (int j = 0; j < 8; ++j)
            acc[j] = __fadd_rn(acc[j], __fmul_rn(r[i + j], r[i + j]));
    float s01 = __fadd_rn(acc[0], acc[1]);
    float s23 = __fadd_rn(acc[2], acc[3]);
    float s45 = __fadd_rn(acc[4], acc[5]);
    float s67 = __fadd_rn(acc[6], acc[7]);
    sqw[p] = __fadd_rn(__fadd_rn(s01, s23), __fadd_rn(s45, s67));
}

// Maintain an ascending sorted 64-list, one u32 per lane:
// (fp32 key bits truncated to 20 | 12-bit idx). Key >= 0 so uint order == key
// order; truncation err 2.4e-4 rel vs rank-32->48 gap ~3.7 => superset safe.
// Threshold = lane 47 (48th smallest). Wave-parallel shift insert.
__device__ __forceinline__ void stream_insert(uint32_t& list, uint32_t cand, int lane) {
    uint32_t thr = (uint32_t)__builtin_amdgcn_readlane((int)list, 47);
    u64 mask = __ballot(cand < thr);
    while (mask) {
        int src = __ffsll((long long)mask) - 1;
        uint32_t v = (uint32_t)__builtin_amdgcn_readlane((int)cand, src);  // uniform src
        int pos = __popcll(__ballot(list < v));
        uint32_t up = __shfl_up(list, 1);
        list = (lane < pos) ? list : ((lane == pos) ? v : up);
        mask &= (mask - 1);
    }
}

// Re-rank the 48 preselected candidates by the emulated reference key:
// key = fl(fl(sq_n - fl(2*inner)) + sq_m), inner = ONE sequential FMA chain
// over k = 0..63 ascending (XLA:CPU dot_general / Eigen gebp order).
__device__ __forceinline__ void epilogue(uint32_t list, int n, int b, int lane,
                                         const float* __restrict__ pb,
                                         const float* __restrict__ sqb,
                                         float sqn,
                                         const float* __restrict__ xyz,
                                         float* __restrict__ out) {
    int m = (int)(list & IDXBITS);        // every lane holds a real index after chunk 0
    const float4* xr = (const float4*)(pb + (size_t)n * NC);
    const float4* yr = (const float4*)(pb + (size_t)m * NC);
    float acc = 0.f;
#pragma unroll
    for (int i = 0; i < 16; ++i) {
        float4 xv = xr[i];
        float4 yv = yr[i];
        acc = __fmaf_rn(xv.x, yv.x, acc);
        acc = __fmaf_rn(xv.y, yv.y, acc);
        acc = __fmaf_rn(xv.z, yv.z, acc);
        acc = __fmaf_rn(xv.w, yv.w, acc);
    }
    float key = __fadd_rn(__fsub_rn(sqn, __fmul_rn(2.0f, acc)), sqb[m]);

    int rank = 0;
    uint32_t kb = __float_as_uint(key);
#pragma unroll 1
    for (int j = 0; j < TSEL; ++j) {
        float kj = __uint_as_float(
            (uint32_t)__builtin_amdgcn_readlane((int)kb, j));
        int mj = __builtin_amdgcn_readlane(m, j);
        bool less = (kj < key) || (kj == key && mj < m);   // stable: lower idx first
        rank += less ? 1 : 0;
    }
    if (lane < TSEL && rank < 2 * KOUT && (rank & 1) == 0) {  // dilation D=2: even ranks
        int k = rank >> 1;
        const float* xn = xyz + ((size_t)b * NPTS + n) * 3;
        const float* xm = xyz + ((size_t)b * NPTS + m) * 3;
        float xnx = xn[0], xny = xn[1], xnz = xn[2];
        float ox = xm[0], oy = xm[1], oz = xm[2];
        float rx = xnx - ox, ry = xny - oy, rz = xnz - oz;
        float dis = sqrtf(rx * rx + ry * ry + rz * rz);
        float* o = out + (((size_t)b * NPTS + n) * KOUT + k) * 10;
        o[0] = dis; o[1] = rx; o[2] = ry; o[3] = rz;
        o[4] = xnx; o[5] = xny; o[6] = xnz;
        o[7] = ox;  o[8] = oy;  o[9] = oz;
    }
}

// 3 waves/SIMD tier (cap ~85). x-rows via SCALAR loads (wave-uniform address
// through readfirstlane -> s_load path, SGPR operands feed v_fma directly):
// zero x VGPR arrays, zero x LDS traffic. y via padded LDS tile (0 conflicts).
__global__ __launch_bounds__(256, 3) void knn_kernel(
    const float* __restrict__ xyz,
    const float* __restrict__ pts,
    const float* __restrict__ sqw,
    float* __restrict__ out) {

    // double-buffered fp32 tile: 2 * 64 rows * 68 floats * 4B = 34.8 KB
    __shared__ __align__(16) float ylds[2][CHUNK * PADROW];

    const int tid = threadIdx.x;
    const int lane = tid & 63;
    const int wave = tid >> 6;
    const int b = blockIdx.x >> 9;                  // 512 blocks per batch
    const int rowbase = (blockIdx.x & 511) << 3;    // 8 rows per block
    // wave-uniform row index, formally uniform via readfirstlane -> scalar loads
    const int n0 = __builtin_amdgcn_readfirstlane(rowbase + wave * 2);
    const int n1 = n0 + 1;
    const float* pb = pts + (size_t)b * NPTS * NC;
    const float* sqb = sqw + (size_t)b * NPTS;

    const float4* xr0 = (const float4*)(pb + (size_t)n0 * NC);  // uniform
    const float4* xr1 = (const float4*)(pb + (size_t)n1 * NC);  // uniform

    const float sqn0 = sqb[n0];    // uniform -> scalar load
    const float sqn1 = sqb[n1];

    uint32_t list0 = 0xFFFFFFFFu, list1 = 0xFFFFFFFFu;

    const float4* gsrc = (const float4*)pb;
    float4 pf[4];
#pragma unroll
    for (int j = 0; j < 4; ++j) pf[j] = gsrc[tid + 256 * j];   // prefetch chunk 0

    // stage chunk 0 into buffer 0
#pragma unroll
    for (int j = 0; j < 4; ++j) {
        int s = tid + 256 * j;
        int ml = s >> 4;
        int c4 = s & 15;
        *(float4*)&ylds[0][ml * PADROW + c4 * 4] = pf[j];
    }
    __syncthreads();

    for (int c = 0; c < NCHUNK; ++c) {
        const int cb = c & 1;
        if (c + 1 < NCHUNK) {
#pragma unroll
            for (int j = 0; j < 4; ++j)
                pf[j] = gsrc[(size_t)(c + 1) * (CHUNK * 16) + tid + 256 * j];
        }
        {
            const int m = c * CHUNK + lane;
            float sqm = sqb[m];           // hoisted: hides under ds_reads
            const float* yr = &ylds[cb][lane * PADROW];
            float a0x = 0.f, a0y = 0.f, a0z = 0.f, a0w = 0.f;
            float a1x = 0.f, a1y = 0.f, a1z = 0.f, a1w = 0.f;
#pragma unroll
            for (int i = 0; i < 16; ++i) {
                float4 y = *(const float4*)(yr + i * 4);
                float4 x0 = xr0[i];       // uniform -> s_load, SGPR operand
                float4 x1 = xr1[i];       // uniform -> s_load, SGPR operand
                a0x = fmaf(x0.x, y.x, a0x);
                a0y = fmaf(x0.y, y.y, a0y);
                a0z = fmaf(x0.z, y.z, a0z);
                a0w = fmaf(x0.w, y.w, a0w);
                a1x = fmaf(x1.x, y.x, a1x);
                a1y = fmaf(x1.y, y.y, a1y);
                a1z = fmaf(x1.z, y.z, a1z);
                a1w = fmaf(x1.w, y.w, a1w);
            }
            float ip0 = (a0x + a0y) + (a0z + a0w);
            float ip1 = (a1x + a1y) + (a1z + a1w);
            // preselect key: ~1e-4 fp error + 2.4e-4 truncation vs margin ~3.7;
            // final ranking is the epilogue's exact emulated key
            float t0 = fmaxf(fmaf(-2.f, ip0, sqn0 + sqm), 0.f);
            float t1 = fmaxf(fmaf(-2.f, ip1, sqn1 + sqm), 0.f);
            uint32_t c0 = (__float_as_uint(t0) & KEYMASK) | (unsigned)m;
            uint32_t c1 = (__float_as_uint(t1) & KEYMASK) | (unsigned)m;
            stream_insert(list0, c0, lane);
            stream_insert(list1, c1, lane);
        }
        if (c + 1 < NCHUNK) {
            const int nbuf = cb ^ 1;
#pragma unroll
            for (int j = 0; j < 4; ++j) {
                int s = tid + 256 * j;
                int ml = s >> 4;
                int c4 = s & 15;
                *(float4*)&ylds[nbuf][ml * PADROW + c4 * 4] = pf[j];
            }
        }
        __syncthreads();   // one barrier per chunk: next buffer fully staged
    }

    epilogue(list0, n0, b, lane, pb, sqb, sqn0, xyz, out);
    epilogue(list1, n1, b, lane, pb, sqb, sqn1, xyz, out);
}

extern "C" void kernel_launch(void* const* d_in, const int* in_sizes, int n_in,
                              void* d_out, int out_size, void* d_ws, size_t ws_size,
                              hipStream_t stream) {
    const float* xyz = (const float*)d_in[0];   // [8,4096,3]
    const float* pts = (const float*)d_in[1];   // [8,4096,64]
    float* sqw = (float*)d_ws;                  // 32768 floats = 128 KB scratch
    float* out = (float*)d_out;                 // [8,4096,16,10]

    sq_kernel<<<(NB * NPTS) / 256, 256, 0, stream>>>(pts, sqw);
    knn_kernel<<<(NB * NPTS) / 8, 256, 0, stream>>>(xyz, pts, sqw, out);
}

// Round 11
// 912.688 us; speedup vs baseline: 2.4964x; 1.3442x over previous
//
#include <hip/hip_runtime.h>
#include <stdint.h>

typedef unsigned long long u64;

#define NB 8
#define NPTS 4096
#define NC 64
#define KOUT 16
#define TSEL 48          // preselect size (top-48 contains true top-32; gap analysis 100x margin)
#define CHUNK 64         // candidate rows per staged chunk
#define PADROW 68        // floats per staged row: 64 + 4 pad -> 0 conflicts (r2/r6/r10 measured)
#define NCHUNK (NPTS / CHUNK)
#define IDXBITS 0xFFFu   // low 12 bits hold candidate index (NPTS = 4096)
#define KEYMASK 0xFFFFF000u
#define RPW 4            // rows per wave (amortizes per-chunk fixed costs)
#define RPB 16           // rows per block (4 waves)

// sq[p]: 8 accumulator chains over stride-8 (numpy pairwise-8 == XLA W8 reduce
// chains), separate mul/add roundings, combined ((r0+r1)+(r2+r3))+((r4+r5)+(r6+r7)).
__global__ __launch_bounds__(256) void sq_kernel(const float* __restrict__ pts,
                                                 float* __restrict__ sqw) {
    int p = blockIdx.x * 256 + threadIdx.x;
    const float* r = pts + (size_t)p * NC;
    float acc[8];
#pragma unroll
    for (int j = 0; j < 8; ++j) acc[j] = __fmul_rn(r[j], r[j]);
#pragma unroll
    for (int i = 8; i < 64; i += 8)
#pragma unroll
        for (int j = 0; j < 8; ++j)
            acc[j] = __fadd_rn(acc[j], __fmul_rn(r[i + j], r[i + j]));
    float s01 = __fadd_rn(acc[0], acc[1]);
    float s23 = __fadd_rn(acc[2], acc[3]);
    float s45 = __fadd_rn(acc[4], acc[5]);
    float s67 = __fadd_rn(acc[6], acc[7]);
    sqw[p] = __fadd_rn(__fadd_rn(s01, s23), __fadd_rn(s45, s67));
}

// Maintain an ascending sorted 64-list, one u32 per lane:
// (fp32 key bits truncated to 20 | 12-bit idx). Key >= 0 so uint order == key
// order; truncation err 2.4e-4 rel vs rank-32->48 gap ~2.9 => superset safe.
// Threshold = lane 47 (48th smallest). Wave-parallel shift insert.
__device__ __forceinline__ void stream_insert(uint32_t& list, uint32_t cand, int lane) {
    uint32_t thr = (uint32_t)__builtin_amdgcn_readlane((int)list, 47);
    u64 mask = __ballot(cand < thr);
    while (mask) {
        int src = __ffsll((long long)mask) - 1;
        uint32_t v = (uint32_t)__builtin_amdgcn_readlane((int)cand, src);  // uniform src
        int pos = __popcll(__ballot(list < v));
        uint32_t up = __shfl_up(list, 1);
        list = (lane < pos) ? list : ((lane == pos) ? v : up);
        mask &= (mask - 1);
    }
}

// Re-rank the 48 preselected candidates by the emulated reference key:
// key = fl(fl(sq_n - fl(2*inner)) + sq_m), inner = ONE sequential FMA chain
// over k = 0..63 ascending (XLA:CPU dot_general / Eigen gebp order).
__device__ __forceinline__ void epilogue(uint32_t list, int n, int b, int lane,
                                         const float* __restrict__ pb,
                                         const float* __restrict__ sqb,
                                         float sqn,
                                         const float* __restrict__ xyz,
                                         float* __restrict__ out) {
    int m = (int)(list & IDXBITS);        // every lane holds a real index after chunk 0
    const float4* xr = (const float4*)(pb + (size_t)n * NC);
    const float4* yr = (const float4*)(pb + (size_t)m * NC);
    float acc = 0.f;
#pragma unroll
    for (int i = 0; i < 16; ++i) {
        float4 xv = xr[i];
        float4 yv = yr[i];
        acc = __fmaf_rn(xv.x, yv.x, acc);
        acc = __fmaf_rn(xv.y, yv.y, acc);
        acc = __fmaf_rn(xv.z, yv.z, acc);
        acc = __fmaf_rn(xv.w, yv.w, acc);
    }
    float key = __fadd_rn(__fsub_rn(sqn, __fmul_rn(2.0f, acc)), sqb[m]);

    int rank = 0;
    uint32_t kb = __float_as_uint(key);
#pragma unroll 1
    for (int j = 0; j < TSEL; ++j) {
        float kj = __uint_as_float(
            (uint32_t)__builtin_amdgcn_readlane((int)kb, j));
        int mj = __builtin_amdgcn_readlane(m, j);
        bool less = (kj < key) || (kj == key && mj < m);   // stable: lower idx first
        rank += less ? 1 : 0;
    }
    if (lane < TSEL && rank < 2 * KOUT && (rank & 1) == 0) {  // dilation D=2: even ranks
        int k = rank >> 1;
        const float* xn = xyz + ((size_t)b * NPTS + n) * 3;
        const float* xm = xyz + ((size_t)b * NPTS + m) * 3;
        float xnx = xn[0], xny = xn[1], xnz = xn[2];
        float ox = xm[0], oy = xm[1], oz = xm[2];
        float rx = xnx - ox, ry = xny - oy, rz = xnz - oz;
        float dis = sqrtf(rx * rx + ry * ry + rz * rz);
        float* o = out + (((size_t)b * NPTS + n) * KOUT + k) * 10;
        o[0] = dis; o[1] = rx; o[2] = ry; o[3] = rz;
        o[4] = xnx; o[5] = xny; o[6] = xnz;
        o[7] = ox;  o[8] = oy;  o[9] = oz;
    }
}

#define ROWFMA(r, xv)                                  \
    acc[r][0] = fmaf(xv.x, y.x, acc[r][0]);            \
    acc[r][1] = fmaf(xv.y, y.y, acc[r][1]);            \
    acc[r][2] = fmaf(xv.z, y.z, acc[r][2]);            \
    acc[r][3] = fmaf(xv.w, y.w, acc[r][3]);

// 4 rows/wave: per-chunk fixed costs (y ds_reads, staging, barrier, sqm)
// amortized 2x vs r10. x-rows via scalar loads (readfirstlane-uniform).
__global__ __launch_bounds__(256, 3) void knn_kernel(
    const float* __restrict__ xyz,
    const float* __restrict__ pts,
    const float* __restrict__ sqw,
    float* __restrict__ out) {

    // double-buffered fp32 tile: 2 * 64 rows * 68 floats * 4B = 34.8 KB
    __shared__ __align__(16) float ylds[2][CHUNK * PADROW];

    const int tid = threadIdx.x;
    const int lane = tid & 63;
    const int wave = tid >> 6;
    const int b = blockIdx.x >> 8;                  // 256 blocks per batch
    const int rowbase = (blockIdx.x & 255) << 4;    // 16 rows per block
    // wave-uniform base row, formally uniform via readfirstlane -> scalar loads
    const int nw = __builtin_amdgcn_readfirstlane(rowbase + wave * RPW);
    const float* pb = pts + (size_t)b * NPTS * NC;
    const float* sqb = sqw + (size_t)b * NPTS;

    const float4* xr0 = (const float4*)(pb + (size_t)(nw + 0) * NC);  // uniform
    const float4* xr1 = (const float4*)(pb + (size_t)(nw + 1) * NC);
    const float4* xr2 = (const float4*)(pb + (size_t)(nw + 2) * NC);
    const float4* xr3 = (const float4*)(pb + (size_t)(nw + 3) * NC);

    const float sqn0 = sqb[nw + 0];    // uniform -> scalar loads
    const float sqn1 = sqb[nw + 1];
    const float sqn2 = sqb[nw + 2];
    const float sqn3 = sqb[nw + 3];

    uint32_t list0 = 0xFFFFFFFFu, list1 = 0xFFFFFFFFu;
    uint32_t list2 = 0xFFFFFFFFu, list3 = 0xFFFFFFFFu;

    const float4* gsrc = (const float4*)pb;
    float4 pf[4];
#pragma unroll
    for (int j = 0; j < 4; ++j) pf[j] = gsrc[tid + 256 * j];   // prefetch chunk 0

    // stage chunk 0 into buffer 0
#pragma unroll
    for (int j = 0; j < 4; ++j) {
        int s = tid + 256 * j;
        int ml = s >> 4;
        int c4 = s & 15;
        *(float4*)&ylds[0][ml * PADROW + c4 * 4] = pf[j];
    }
    __syncthreads();

    for (int c = 0; c < NCHUNK; ++c) {
        const int cb = c & 1;
        if (c + 1 < NCHUNK) {
#pragma unroll
            for (int j = 0; j < 4; ++j)
                pf[j] = gsrc[(size_t)(c + 1) * (CHUNK * 16) + tid + 256 * j];
        }
        {
            const int m = c * CHUNK + lane;
            float sqm = sqb[m];           // hoisted: hides under ds_reads
            const float* yr = &ylds[cb][lane * PADROW];
            float acc[RPW][4] = {};
#pragma unroll
            for (int i = 0; i < 16; ++i) {
                float4 y = *(const float4*)(yr + i * 4);
                float4 x0 = xr0[i];       // uniform -> s_load, SGPR operands
                float4 x1 = xr1[i];
                float4 x2 = xr2[i];
                float4 x3 = xr3[i];
                ROWFMA(0, x0)
                ROWFMA(1, x1)
                ROWFMA(2, x2)
                ROWFMA(3, x3)
            }
            float ip0 = (acc[0][0] + acc[0][1]) + (acc[0][2] + acc[0][3]);
            float ip1 = (acc[1][0] + acc[1][1]) + (acc[1][2] + acc[1][3]);
            float ip2 = (acc[2][0] + acc[2][1]) + (acc[2][2] + acc[2][3]);
            float ip3 = (acc[3][0] + acc[3][1]) + (acc[3][2] + acc[3][3]);
            // preselect key: ~1e-4 fp error + 2.4e-4 truncation vs margin ~2.9;
            // final ranking is the epilogue's exact emulated key
            float t0 = fmaxf(fmaf(-2.f, ip0, sqn0 + sqm), 0.f);
            float t1 = fmaxf(fmaf(-2.f, ip1, sqn1 + sqm), 0.f);
            float t2 = fmaxf(fmaf(-2.f, ip2, sqn2 + sqm), 0.f);
            float t3 = fmaxf(fmaf(-2.f, ip3, sqn3 + sqm), 0.f);
            uint32_t c0 = (__float_as_uint(t0) & KEYMASK) | (unsigned)m;
            uint32_t c1 = (__float_as_uint(t1) & KEYMASK) | (unsigned)m;
            uint32_t c2 = (__float_as_uint(t2) & KEYMASK) | (unsigned)m;
            uint32_t c3 = (__float_as_uint(t3) & KEYMASK) | (unsigned)m;
            stream_insert(list0, c0, lane);
            stream_insert(list1, c1, lane);
            stream_insert(list2, c2, lane);
            stream_insert(list3, c3, lane);
        }
        if (c + 1 < NCHUNK) {
            const int nbuf = cb ^ 1;
#pragma unroll
            for (int j = 0; j < 4; ++j) {
                int s = tid + 256 * j;
                int ml = s >> 4;
                int c4 = s & 15;
                *(float4*)&ylds[nbuf][ml * PADROW + c4 * 4] = pf[j];
            }
        }
        __syncthreads();   // one barrier per chunk: next buffer fully staged
    }

    epilogue(list0, nw + 0, b, lane, pb, sqb, sqn0, xyz, out);
    epilogue(list1, nw + 1, b, lane, pb, sqb, sqn1, xyz, out);
    epilogue(list2, nw + 2, b, lane, pb, sqb, sqn2, xyz, out);
    epilogue(list3, nw + 3, b, lane, pb, sqb, sqn3, xyz, out);
}

extern "C" void kernel_launch(void* const* d_in, const int* in_sizes, int n_in,
                              void* d_out, int out_size, void* d_ws, size_t ws_size,
                              hipStream_t stream) {
    const float* xyz = (const float*)d_in[0];   // [8,4096,3]
    const float* pts = (const float*)d_in[1];   // [8,4096,64]
    float* sqw = (float*)d_ws;                  // 32768 floats = 128 KB scratch
    float* out = (float*)d_out;                 // [8,4096,16,10]

    sq_kernel<<<(NB * NPTS) / 256, 256, 0, stream>>>(pts, sqw);
    knn_kernel<<<(NB * NPTS) / RPB, 256, 0, stream>>>(xyz, pts, sqw, out);
}

// Round 12
// 850.622 us; speedup vs baseline: 2.6785x; 1.0730x over previous
//
#include <hip/hip_runtime.h>
#include <stdint.h>

typedef unsigned long long u64;
typedef float f32x2 __attribute__((ext_vector_type(2)));
typedef float f32x4 __attribute__((ext_vector_type(4)));

#define NB 8
#define NPTS 4096
#define NC 64
#define KOUT 16
#define TSEL 48          // preselect size (top-48 contains true top-32; gap analysis 100x margin)
#define CHUNK 64         // candidate rows per staged chunk
#define PADROW 68        // floats per staged row: 64 + 4 pad -> 0 conflicts (r2/r6/r10/r11 measured)
#define NCHUNK (NPTS / CHUNK)
#define IDXBITS 0xFFFu   // low 12 bits hold candidate index (NPTS = 4096)
#define KEYMASK 0xFFFFF000u
#define RPW 4            // rows per wave (amortizes per-chunk fixed costs)
#define RPB 16           // rows per block (4 waves)

// sq[p]: 8 accumulator chains over stride-8 (numpy pairwise-8 == XLA W8 reduce
// chains), separate mul/add roundings, combined ((r0+r1)+(r2+r3))+((r4+r5)+(r6+r7)).
__global__ __launch_bounds__(256) void sq_kernel(const float* __restrict__ pts,
                                                 float* __restrict__ sqw) {
    int p = blockIdx.x * 256 + threadIdx.x;
    const float* r = pts + (size_t)p * NC;
    float acc[8];
#pragma unroll
    for (int j = 0; j < 8; ++j) acc[j] = __fmul_rn(r[j], r[j]);
#pragma unroll
    for (int i = 8; i < 64; i += 8)
#pragma unroll
        for (int j = 0; j < 8; ++j)
            acc[j] = __fadd_rn(acc[j], __fmul_rn(r[i + j], r[i + j]));
    float s01 = __fadd_rn(acc[0], acc[1]);
    float s23 = __fadd_rn(acc[2], acc[3]);
    float s45 = __fadd_rn(acc[4], acc[5]);
    float s67 = __fadd_rn(acc[6], acc[7]);
    sqw[p] = __fadd_rn(__fadd_rn(s01, s23), __fadd_rn(s45, s67));
}

// Maintain an ascending sorted 64-list, one u32 per lane:
// (fp32 key bits truncated to 20 | 12-bit idx). Key >= 0 so uint order == key
// order; truncation err 2.4e-4 rel vs rank-32->48 gap ~2.9 => superset safe.
// Threshold = lane 47 (48th smallest). Wave-parallel shift insert.
__device__ __forceinline__ void stream_insert(uint32_t& list, uint32_t cand, int lane) {
    uint32_t thr = (uint32_t)__builtin_amdgcn_readlane((int)list, 47);
    u64 mask = __ballot(cand < thr);
    while (mask) {
        int src = __ffsll((long long)mask) - 1;
        uint32_t v = (uint32_t)__builtin_amdgcn_readlane((int)cand, src);  // uniform src
        int pos = __popcll(__ballot(list < v));
        uint32_t up = __shfl_up(list, 1);
        list = (lane < pos) ? list : ((lane == pos) ? v : up);
        mask &= (mask - 1);
    }
}

// Re-rank the 48 preselected candidates by the emulated reference key:
// key = fl(fl(sq_n - fl(2*inner)) + sq_m), inner = ONE sequential FMA chain
// over k = 0..63 ascending (XLA:CPU dot_general / Eigen gebp order).
__device__ __forceinline__ void epilogue(uint32_t list, int n, int b, int lane,
                                         const float* __restrict__ pb,
                                         const float* __restrict__ sqb,
                                         float sqn,
                                         const float* __restrict__ xyz,
                                         float* __restrict__ out) {
    int m = (int)(list & IDXBITS);        // every lane holds a real index after chunk 0
    const float4* xr = (const float4*)(pb + (size_t)n * NC);
    const float4* yr = (const float4*)(pb + (size_t)m * NC);
    float acc = 0.f;
#pragma unroll
    for (int i = 0; i < 16; ++i) {
        float4 xv = xr[i];
        float4 yv = yr[i];
        acc = __fmaf_rn(xv.x, yv.x, acc);
        acc = __fmaf_rn(xv.y, yv.y, acc);
        acc = __fmaf_rn(xv.z, yv.z, acc);
        acc = __fmaf_rn(xv.w, yv.w, acc);
    }
    float key = __fadd_rn(__fsub_rn(sqn, __fmul_rn(2.0f, acc)), sqb[m]);

    int rank = 0;
    uint32_t kb = __float_as_uint(key);
#pragma unroll 1
    for (int j = 0; j < TSEL; ++j) {
        float kj = __uint_as_float(
            (uint32_t)__builtin_amdgcn_readlane((int)kb, j));
        int mj = __builtin_amdgcn_readlane(m, j);
        bool less = (kj < key) || (kj == key && mj < m);   // stable: lower idx first
        rank += less ? 1 : 0;
    }
    if (lane < TSEL && rank < 2 * KOUT && (rank & 1) == 0) {  // dilation D=2: even ranks
        int k = rank >> 1;
        const float* xn = xyz + ((size_t)b * NPTS + n) * 3;
        const float* xm = xyz + ((size_t)b * NPTS + m) * 3;
        float xnx = xn[0], xny = xn[1], xnz = xn[2];
        float ox = xm[0], oy = xm[1], oz = xm[2];
        float rx = xnx - ox, ry = xny - oy, rz = xnz - oz;
        float dis = sqrtf(rx * rx + ry * ry + rz * rz);
        float* o = out + (((size_t)b * NPTS + n) * KOUT + k) * 10;
        o[0] = dis; o[1] = rx; o[2] = ry; o[3] = rz;
        o[4] = xnx; o[5] = xny; o[6] = xnz;
        o[7] = ox;  o[8] = oy;  o[9] = oz;
    }
}

// packed fp32 FMA: acc[r][0] carries the {comp-x, comp-y} chains, acc[r][1]
// the {comp-z, comp-w} chains -> v_pk_fma_f32 (2 FMA/inst), math identical
// to four scalar __fmaf_rn chains.
#define ROWFMA(r, xa, xb)                                          \
    acc[r][0] = __builtin_elementwise_fma(xa, ylo, acc[r][0]);     \
    acc[r][1] = __builtin_elementwise_fma(xb, yhi, acc[r][1]);

// 4 rows/wave; x-rows via scalar loads (readfirstlane-uniform). VGPR demand
// ~52 (r11 measured) -> fits the 4-waves/SIMD tier; LDS 4x34.8KB=139<=160KB.
__global__ __launch_bounds__(256, 4) void knn_kernel(
    const float* __restrict__ xyz,
    const float* __restrict__ pts,
    const float* __restrict__ sqw,
    float* __restrict__ out) {

    // double-buffered fp32 tile: 2 * 64 rows * 68 floats * 4B = 34.8 KB
    __shared__ __align__(16) float ylds[2][CHUNK * PADROW];

    const int tid = threadIdx.x;
    const int lane = tid & 63;
    const int wave = tid >> 6;
    const int b = blockIdx.x >> 8;                  // 256 blocks per batch
    const int rowbase = (blockIdx.x & 255) << 4;    // 16 rows per block
    // wave-uniform base row, formally uniform via readfirstlane -> scalar loads
    const int nw = __builtin_amdgcn_readfirstlane(rowbase + wave * RPW);
    const float* pb = pts + (size_t)b * NPTS * NC;
    const float* sqb = sqw + (size_t)b * NPTS;

    const f32x2* xp0 = (const f32x2*)(pb + (size_t)(nw + 0) * NC);  // uniform
    const f32x2* xp1 = (const f32x2*)(pb + (size_t)(nw + 1) * NC);
    const f32x2* xp2 = (const f32x2*)(pb + (size_t)(nw + 2) * NC);
    const f32x2* xp3 = (const f32x2*)(pb + (size_t)(nw + 3) * NC);

    const float sqn0 = sqb[nw + 0];    // uniform -> scalar loads
    const float sqn1 = sqb[nw + 1];
    const float sqn2 = sqb[nw + 2];
    const float sqn3 = sqb[nw + 3];

    uint32_t list0 = 0xFFFFFFFFu, list1 = 0xFFFFFFFFu;
    uint32_t list2 = 0xFFFFFFFFu, list3 = 0xFFFFFFFFu;

    const float4* gsrc = (const float4*)pb;
    float4 pf[4];
#pragma unroll
    for (int j = 0; j < 4; ++j) pf[j] = gsrc[tid + 256 * j];   // prefetch chunk 0

    // stage chunk 0 into buffer 0
#pragma unroll
    for (int j = 0; j < 4; ++j) {
        int s = tid + 256 * j;
        int ml = s >> 4;
        int c4 = s & 15;
        *(float4*)&ylds[0][ml * PADROW + c4 * 4] = pf[j];
    }
    __syncthreads();

    for (int c = 0; c < NCHUNK; ++c) {
        const int cb = c & 1;
        if (c + 1 < NCHUNK) {
#pragma unroll
            for (int j = 0; j < 4; ++j)
                pf[j] = gsrc[(size_t)(c + 1) * (CHUNK * 16) + tid + 256 * j];
        }
        {
            const int m = c * CHUNK + lane;
            float sqm = sqb[m];           // hoisted: hides under ds_reads
            const float* yr = &ylds[cb][lane * PADROW];
            f32x2 acc[RPW][2] = {};
#pragma unroll
            for (int i = 0; i < 16; ++i) {
                f32x4 y4 = *(const f32x4*)(yr + i * 4);
                f32x2 ylo = __builtin_shufflevector(y4, y4, 0, 1);
                f32x2 yhi = __builtin_shufflevector(y4, y4, 2, 3);
                f32x2 x0a = xp0[2 * i], x0b = xp0[2 * i + 1];   // s_load pairs
                f32x2 x1a = xp1[2 * i], x1b = xp1[2 * i + 1];
                f32x2 x2a = xp2[2 * i], x2b = xp2[2 * i + 1];
                f32x2 x3a = xp3[2 * i], x3b = xp3[2 * i + 1];
                ROWFMA(0, x0a, x0b)
                ROWFMA(1, x1a, x1b)
                ROWFMA(2, x2a, x2b)
                ROWFMA(3, x3a, x3b)
            }
            float ip0 = (acc[0][0].x + acc[0][0].y) + (acc[0][1].x + acc[0][1].y);
            float ip1 = (acc[1][0].x + acc[1][0].y) + (acc[1][1].x + acc[1][1].y);
            float ip2 = (acc[2][0].x + acc[2][0].y) + (acc[2][1].x + acc[2][1].y);
            float ip3 = (acc[3][0].x + acc[3][0].y) + (acc[3][1].x + acc[3][1].y);
            // preselect key: ~1e-4 fp error + 2.4e-4 truncation vs margin ~2.9;
            // final ranking is the epilogue's exact emulated key
            float t0 = fmaxf(fmaf(-2.f, ip0, sqn0 + sqm), 0.f);
            float t1 = fmaxf(fmaf(-2.f, ip1, sqn1 + sqm), 0.f);
            float t2 = fmaxf(fmaf(-2.f, ip2, sqn2 + sqm), 0.f);
            float t3 = fmaxf(fmaf(-2.f, ip3, sqn3 + sqm), 0.f);
            uint32_t c0 = (__float_as_uint(t0) & KEYMASK) | (unsigned)m;
            uint32_t c1 = (__float_as_uint(t1) & KEYMASK) | (unsigned)m;
            uint32_t c2 = (__float_as_uint(t2) & KEYMASK) | (unsigned)m;
            uint32_t c3 = (__float_as_uint(t3) & KEYMASK) | (unsigned)m;
            stream_insert(list0, c0, lane);
            stream_insert(list1, c1, lane);
            stream_insert(list2, c2, lane);
            stream_insert(list3, c3, lane);
        }
        if (c + 1 < NCHUNK) {
            const int nbuf = cb ^ 1;
#pragma unroll
            for (int j = 0; j < 4; ++j) {
                int s = tid + 256 * j;
                int ml = s >> 4;
                int c4 = s & 15;
                *(float4*)&ylds[nbuf][ml * PADROW + c4 * 4] = pf[j];
            }
        }
        __syncthreads();   // one barrier per chunk: next buffer fully staged
    }

    epilogue(list0, nw + 0, b, lane, pb, sqb, sqn0, xyz, out);
    epilogue(list1, nw + 1, b, lane, pb, sqb, sqn1, xyz, out);
    epilogue(list2, nw + 2, b, lane, pb, sqb, sqn2, xyz, out);
    epilogue(list3, nw + 3, b, lane, pb, sqb, sqn3, xyz, out);
}

extern "C" void kernel_launch(void* const* d_in, const int* in_sizes, int n_in,
                              void* d_out, int out_size, void* d_ws, size_t ws_size,
                              hipStream_t stream) {
    const float* xyz = (const float*)d_in[0];   // [8,4096,3]
    const float* pts = (const float*)d_in[1];   // [8,4096,64]
    float* sqw = (float*)d_ws;                  // 32768 floats = 128 KB scratch
    float* out = (float*)d_out;                 // [8,4096,16,10]

    sq_kernel<<<(NB * NPTS) / 256, 256, 0, stream>>>(pts, sqw);
    knn_kernel<<<(NB * NPTS) / RPB, 256, 0, stream>>>(xyz, pts, sqw, out);
}

// Round 13
// 415.483 us; speedup vs baseline: 5.4838x; 2.0473x over previous
//
#include <hip/hip_runtime.h>
#include <stdint.h>

typedef unsigned long long u64;
typedef __attribute__((ext_vector_type(8))) short s16x8;     // 8 bf16 = 4 VGPRs
typedef __attribute__((ext_vector_type(4))) float f32x4v;
typedef __attribute__((ext_vector_type(4))) unsigned int u32x4;
typedef __attribute__((ext_vector_type(2))) unsigned int u32x2;

#define NB 8
#define NPTS 4096
#define NC 64
#define KOUT 16
#define TSEL 48          // preselect size; bf16 key err ~0.1 << rank-32->48 gap ~2.9
#define CHUNK 64         // candidate rows per staged chunk
#define NCHUNK (NPTS / CHUNK)
#define IDXBITS 0xFFFu
#define KEYMASK 0xFFFFF000u
#define RPW 4            // rows per wave
#define RPB 16           // rows per block (4 waves)
#define ROWB 144         // bytes per Y LDS row: 64 bf16 (128B) + 16B pad (2-way banks = free)

// sq[p]: 8 accumulator chains over stride-8 (numpy pairwise-8 == XLA W8 reduce
// chains), separate mul/add roundings, combined ((r0+r1)+(r2+r3))+((r4+r5)+(r6+r7)).
__global__ __launch_bounds__(256) void sq_kernel(const float* __restrict__ pts,
                                                 float* __restrict__ sqw) {
    int p = blockIdx.x * 256 + threadIdx.x;
    const float* r = pts + (size_t)p * NC;
    float acc[8];
#pragma unroll
    for (int j = 0; j < 8; ++j) acc[j] = __fmul_rn(r[j], r[j]);
#pragma unroll
    for (int i = 8; i < 64; i += 8)
#pragma unroll
        for (int j = 0; j < 8; ++j)
            acc[j] = __fadd_rn(acc[j], __fmul_rn(r[i + j], r[i + j]));
    float s01 = __fadd_rn(acc[0], acc[1]);
    float s23 = __fadd_rn(acc[2], acc[3]);
    float s45 = __fadd_rn(acc[4], acc[5]);
    float s67 = __fadd_rn(acc[6], acc[7]);
    sqw[p] = __fadd_rn(__fadd_rn(s01, s23), __fadd_rn(s45, s67));
}

// pack two fp32 -> u32 of two bf16 (truncation; pure bit-move, b in high half)
static __device__ __forceinline__ uint32_t pkbf(float a, float b) {
#if __has_builtin(__builtin_amdgcn_perm)
    return __builtin_amdgcn_perm(__float_as_uint(b), __float_as_uint(a), 0x07060302);
#else
    return (__float_as_uint(b) & 0xFFFF0000u) | (__float_as_uint(a) >> 16);
#endif
}

// Maintain an ascending sorted 64-list, one u32 per lane:
// (fp32 key bits truncated to 20 | 12-bit idx). Key >= 0 so uint order == key
// order. Threshold = lane 47 (48th smallest). Wave-parallel shift insert.
__device__ __forceinline__ void stream_insert(uint32_t& list, uint32_t cand, int lane) {
    uint32_t thr = (uint32_t)__builtin_amdgcn_readlane((int)list, 47);
    u64 mask = __ballot(cand < thr);
    while (mask) {
        int src = __ffsll((long long)mask) - 1;
        uint32_t v = (uint32_t)__builtin_amdgcn_readlane((int)cand, src);  // uniform src
        int pos = __popcll(__ballot(list < v));
        uint32_t up = __shfl_up(list, 1);
        list = (lane < pos) ? list : ((lane == pos) ? v : up);
        mask &= (mask - 1);
    }
}

// Re-rank the 48 preselected candidates by the emulated reference key:
// key = fl(fl(sq_n - fl(2*inner)) + sq_m), inner = ONE sequential FMA chain
// over k = 0..63 ascending (XLA:CPU dot_general / Eigen gebp order).
__device__ __forceinline__ void epilogue(uint32_t list, int n, int b, int lane,
                                         const float* __restrict__ pb,
                                         const float* __restrict__ sqb,
                                         float sqn,
                                         const float* __restrict__ xyz,
                                         float* __restrict__ out) {
    int m = (int)(list & IDXBITS);        // every lane holds a real index after chunk 0
    const float4* xr = (const float4*)(pb + (size_t)n * NC);
    const float4* yr = (const float4*)(pb + (size_t)m * NC);
    float acc = 0.f;
#pragma unroll
    for (int i = 0; i < 16; ++i) {
        float4 xv = xr[i];
        float4 yv = yr[i];
        acc = __fmaf_rn(xv.x, yv.x, acc);
        acc = __fmaf_rn(xv.y, yv.y, acc);
        acc = __fmaf_rn(xv.z, yv.z, acc);
        acc = __fmaf_rn(xv.w, yv.w, acc);
    }
    float key = __fadd_rn(__fsub_rn(sqn, __fmul_rn(2.0f, acc)), sqb[m]);

    int rank = 0;
    uint32_t kb = __float_as_uint(key);
#pragma unroll 1
    for (int j = 0; j < TSEL; ++j) {
        float kj = __uint_as_float(
            (uint32_t)__builtin_amdgcn_readlane((int)kb, j));
        int mj = __builtin_amdgcn_readlane(m, j);
        bool less = (kj < key) || (kj == key && mj < m);   // stable: lower idx first
        rank += less ? 1 : 0;
    }
    if (lane < TSEL && rank < 2 * KOUT && (rank & 1) == 0) {  // dilation D=2: even ranks
        int k = rank >> 1;
        const float* xn = xyz + ((size_t)b * NPTS + n) * 3;
        const float* xm = xyz + ((size_t)b * NPTS + m) * 3;
        float xnx = xn[0], xny = xn[1], xnz = xn[2];
        float ox = xm[0], oy = xm[1], oz = xm[2];
        float rx = xnx - ox, ry = xny - oy, rz = xnz - oz;
        float dis = sqrtf(rx * rx + ry * ry + rz * rz);
        float* o = out + (((size_t)b * NPTS + n) * KOUT + k) * 10;
        o[0] = dis; o[1] = rx; o[2] = ry; o[3] = rz;
        o[4] = xnx; o[5] = xny; o[6] = xnz;
        o[7] = ox;  o[8] = oy;  o[9] = oz;
    }
}

// MFMA preselect: per chunk each wave computes S = X(16x64)·Y^T(64x64) via
// 8x mfma_f32_16x16x32_bf16 (4 N-tiles x 2 K-halves; all 16 block rows,
// redundant across waves - matrix pipe is otherwise idle). A/B fragments use
// the SAME (lane-group, slot)->feature mapping, so the dot is correct under
// any HW k-ordering (k-permutation invariance). C layout (m89-verified):
// col=lane&15, row=(lane>>4)*4+reg. Redistribution to cand-per-lane via an
// intra-wave LDS bounce (DS ops are in-order per wave; no barrier).
__global__ __launch_bounds__(256, 3) void knn_kernel(
    const float* __restrict__ xyz,
    const float* __restrict__ pts,
    const float* __restrict__ sqw,
    float* __restrict__ out) {

    __shared__ __align__(16) unsigned short ylds[2][CHUNK * (ROWB / 2)];  // 18.4 KB bf16 dbuf
    __shared__ __align__(16) float slds[4][CHUNK][4];                     //  4.0 KB key bounce

    const int tid = threadIdx.x;
    const int lane = tid & 63;
    const int wave = tid >> 6;
    const int b = blockIdx.x >> 8;                  // 256 blocks per batch
    const int rowbase = (blockIdx.x & 255) << 4;    // 16 rows per block
    const int nw = __builtin_amdgcn_readfirstlane(rowbase + wave * RPW);
    const float* pb = pts + (size_t)b * NPTS * NC;
    const float* sqb = sqw + (size_t)b * NPTS;

    // A fragments (once per block): lane holds query row (lane&15), feats
    // (lane>>4)*8 + {0..7} (+32 for the K=32..63 fragment), packed bf16.
    s16x8 afrag0, afrag1;
    {
        const float* xrow = pb + (size_t)(rowbase + (lane & 15)) * NC + (lane >> 4) * 8;
        float4 xa0 = *(const float4*)(xrow);
        float4 xa1 = *(const float4*)(xrow + 4);
        float4 xb0 = *(const float4*)(xrow + 32);
        float4 xb1 = *(const float4*)(xrow + 36);
        u32x4 a0p = { pkbf(xa0.x, xa0.y), pkbf(xa0.z, xa0.w),
                      pkbf(xa1.x, xa1.y), pkbf(xa1.z, xa1.w) };
        u32x4 a1p = { pkbf(xb0.x, xb0.y), pkbf(xb0.z, xb0.w),
                      pkbf(xb1.x, xb1.y), pkbf(xb1.z, xb1.w) };
        afrag0 = __builtin_bit_cast(s16x8, a0p);
        afrag1 = __builtin_bit_cast(s16x8, a1p);
    }

    const float sqn0 = sqb[nw + 0];    // uniform -> scalar loads
    const float sqn1 = sqb[nw + 1];
    const float sqn2 = sqb[nw + 2];
    const float sqn3 = sqb[nw + 3];

    uint32_t list0 = 0xFFFFFFFFu, list1 = 0xFFFFFFFFu;
    uint32_t list2 = 0xFFFFFFFFu, list3 = 0xFFFFFFFFu;

    const float4* gsrc = (const float4*)pb;
    float4 pf[4];
#pragma unroll
    for (int j = 0; j < 4; ++j) pf[j] = gsrc[tid + 256 * j];   // prefetch chunk 0

    // stage chunk 0 into buffer 0 (fp32 -> bf16 pack; write pattern hits all
    // 32 banks exactly once per 16-lane phase)
#pragma unroll
    for (int j = 0; j < 4; ++j) {
        int s = tid + 256 * j;
        u32x2 w2 = { pkbf(pf[j].x, pf[j].y), pkbf(pf[j].z, pf[j].w) };
        *(u32x2*)((char*)ylds[0] + (s >> 4) * ROWB + (s & 15) * 8) = w2;
    }
    __syncthreads();

    float* sw = &slds[wave][0][0];

    for (int c = 0; c < NCHUNK; ++c) {
        const int cb = c & 1;
        if (c + 1 < NCHUNK) {
#pragma unroll
            for (int j = 0; j < 4; ++j)
                pf[j] = gsrc[(size_t)(c + 1) * (CHUNK * 16) + tid + 256 * j];
        }
        {
            const int m = c * CHUNK + lane;
            float sqm = sqb[m];
            const char* yb = (const char*)ylds[cb];
            const int bofs = (lane & 15) * ROWB + (lane >> 4) * 16;
#pragma unroll
            for (int t = 0; t < 4; ++t) {
                const char* bp = yb + t * (16 * ROWB) + bofs;
                s16x8 b0 = *(const s16x8*)(bp);        // K 0..31 fragment
                s16x8 b1 = *(const s16x8*)(bp + 64);   // K 32..63 fragment
                f32x4v cc = {0.f, 0.f, 0.f, 0.f};
                cc = __builtin_amdgcn_mfma_f32_16x16x32_bf16(afrag0, b0, cc, 0, 0, 0);
                cc = __builtin_amdgcn_mfma_f32_16x16x32_bf16(afrag1, b1, cc, 0, 0, 0);
                // lanes 16w..16w+15 hold this wave's 4 query rows (regs 0..3)
                if ((lane >> 4) == wave)
                    *(f32x4v*)(sw + (16 * t + (lane & 15)) * 4) = cc;
            }
            // intra-wave bounce: lane reads its cand's 4 query keys (16B)
            f32x4v ip = *(const f32x4v*)(sw + lane * 4);
            float t0 = fmaxf(fmaf(-2.f, ip.x, sqn0 + sqm), 0.f);
            float t1 = fmaxf(fmaf(-2.f, ip.y, sqn1 + sqm), 0.f);
            float t2 = fmaxf(fmaf(-2.f, ip.z, sqn2 + sqm), 0.f);
            float t3 = fmaxf(fmaf(-2.f, ip.w, sqn3 + sqm), 0.f);
            uint32_t c0 = (__float_as_uint(t0) & KEYMASK) | (unsigned)m;
            uint32_t c1 = (__float_as_uint(t1) & KEYMASK) | (unsigned)m;
            uint32_t c2 = (__float_as_uint(t2) & KEYMASK) | (unsigned)m;
            uint32_t c3 = (__float_as_uint(t3) & KEYMASK) | (unsigned)m;
            stream_insert(list0, c0, lane);
            stream_insert(list1, c1, lane);
            stream_insert(list2, c2, lane);
            stream_insert(list3, c3, lane);
        }
        if (c + 1 < NCHUNK) {
#pragma unroll
            for (int j = 0; j < 4; ++j) {
                int s = tid + 256 * j;
                u32x2 w2 = { pkbf(pf[j].x, pf[j].y), pkbf(pf[j].z, pf[j].w) };
                *(u32x2*)((char*)ylds[cb ^ 1] + (s >> 4) * ROWB + (s & 15) * 8) = w2;
            }
        }
        __syncthreads();   // one barrier per chunk: next buffer fully staged
    }

    epilogue(list0, nw + 0, b, lane, pb, sqb, sqn0, xyz, out);
    epilogue(list1, nw + 1, b, lane, pb, sqb, sqn1, xyz, out);
    epilogue(list2, nw + 2, b, lane, pb, sqb, sqn2, xyz, out);
    epilogue(list3, nw + 3, b, lane, pb, sqb, sqn3, xyz, out);
}

extern "C" void kernel_launch(void* const* d_in, const int* in_sizes, int n_in,
                              void* d_out, int out_size, void* d_ws, size_t ws_size,
                              hipStream_t stream) {
    const float* xyz = (const float*)d_in[0];   // [8,4096,3]
    const float* pts = (const float*)d_in[1];   // [8,4096,64]
    float* sqw = (float*)d_ws;                  // 32768 floats = 128 KB scratch
    float* out = (float*)d_out;                 // [8,4096,16,10]

    sq_kernel<<<(NB * NPTS) / 256, 256, 0, stream>>>(pts, sqw);
    knn_kernel<<<(NB * NPTS) / RPB, 256, 0, stream>>>(xyz, pts, sqw, out);
}

// Round 14
// 398.966 us; speedup vs baseline: 5.7108x; 1.0414x over previous
//
#include <hip/hip_runtime.h>
#include <stdint.h>

typedef unsigned long long u64;
typedef __attribute__((ext_vector_type(8))) short s16x8;     // 8 bf16 = 4 VGPRs
typedef __attribute__((ext_vector_type(4))) float f32x4v;
typedef __attribute__((ext_vector_type(4))) unsigned int u32x4;
typedef __attribute__((ext_vector_type(2))) unsigned int u32x2;

#define NB 8
#define NPTS 4096
#define NC 64
#define KOUT 16
#define TSEL 48          // preselect size; bf16 key err ~0.1 << rank-32->48 gap ~2.9
#define CHUNK 64         // candidate rows per staged chunk
#define NCHUNK (NPTS / CHUNK)
#define IDXBITS 0xFFFu
#define KEYMASK 0xFFFFF000u
#define RPW 4            // rows per wave
#define RPB 16           // rows per block (4 waves)
#define ROWB 144         // bytes per Y LDS row: 64 bf16 (128B) + 16B pad (2-way banks = free)

// sq[p]: 8 accumulator chains over stride-8 (numpy pairwise-8 == XLA W8 reduce
// chains), separate mul/add roundings, combined ((r0+r1)+(r2+r3))+((r4+r5)+(r6+r7)).
__global__ __launch_bounds__(256) void sq_kernel(const float* __restrict__ pts,
                                                 float* __restrict__ sqw) {
    int p = blockIdx.x * 256 + threadIdx.x;
    const float* r = pts + (size_t)p * NC;
    float acc[8];
#pragma unroll
    for (int j = 0; j < 8; ++j) acc[j] = __fmul_rn(r[j], r[j]);
#pragma unroll
    for (int i = 8; i < 64; i += 8)
#pragma unroll
        for (int j = 0; j < 8; ++j)
            acc[j] = __fadd_rn(acc[j], __fmul_rn(r[i + j], r[i + j]));
    float s01 = __fadd_rn(acc[0], acc[1]);
    float s23 = __fadd_rn(acc[2], acc[3]);
    float s45 = __fadd_rn(acc[4], acc[5]);
    float s67 = __fadd_rn(acc[6], acc[7]);
    sqw[p] = __fadd_rn(__fadd_rn(s01, s23), __fadd_rn(s45, s67));
}

// pack two fp32 -> u32 of two bf16 (truncation; pure bit-move, b in high half)
static __device__ __forceinline__ uint32_t pkbf(float a, float b) {
#if __has_builtin(__builtin_amdgcn_perm)
    return __builtin_amdgcn_perm(__float_as_uint(b), __float_as_uint(a), 0x07060302);
#else
    return (__float_as_uint(b) & 0xFFFF0000u) | (__float_as_uint(a) >> 16);
#endif
}

// Maintain an ascending sorted 64-list, one u32 per lane:
// (fp32 key bits truncated to 20 | 12-bit idx). Key >= 0 so uint order == key
// order. Threshold = lane 47 (48th smallest). Wave-parallel shift insert.
__device__ __forceinline__ void stream_insert(uint32_t& list, uint32_t cand, int lane) {
    uint32_t thr = (uint32_t)__builtin_amdgcn_readlane((int)list, 47);
    u64 mask = __ballot(cand < thr);
    while (mask) {
        int src = __ffsll((long long)mask) - 1;
        uint32_t v = (uint32_t)__builtin_amdgcn_readlane((int)cand, src);  // uniform src
        int pos = __popcll(__ballot(list < v));
        uint32_t up = __shfl_up(list, 1);
        list = (lane < pos) ? list : ((lane == pos) ? v : up);
        mask &= (mask - 1);
    }
}

// Re-rank the 48 preselected candidates by the emulated reference key:
// key = fl(fl(sq_n - fl(2*inner)) + sq_m), inner = ONE sequential FMA chain
// over k = 0..63 ascending (XLA:CPU dot_general / Eigen gebp order).
__device__ __forceinline__ void epilogue(uint32_t list, int n, int b, int lane,
                                         const float* __restrict__ pb,
                                         const float* __restrict__ sqb,
                                         float sqn,
                                         const float* __restrict__ xyz,
                                         float* __restrict__ out) {
    int m = (int)(list & IDXBITS);        // every lane holds a real index after chunk 0
    const float4* xr = (const float4*)(pb + (size_t)n * NC);
    const float4* yr = (const float4*)(pb + (size_t)m * NC);
    float acc = 0.f;
#pragma unroll
    for (int i = 0; i < 16; ++i) {
        float4 xv = xr[i];
        float4 yv = yr[i];
        acc = __fmaf_rn(xv.x, yv.x, acc);
        acc = __fmaf_rn(xv.y, yv.y, acc);
        acc = __fmaf_rn(xv.z, yv.z, acc);
        acc = __fmaf_rn(xv.w, yv.w, acc);
    }
    float key = __fadd_rn(__fsub_rn(sqn, __fmul_rn(2.0f, acc)), sqb[m]);

    int rank = 0;
    uint32_t kb = __float_as_uint(key);
#pragma unroll 1
    for (int j = 0; j < TSEL; ++j) {
        float kj = __uint_as_float(
            (uint32_t)__builtin_amdgcn_readlane((int)kb, j));
        int mj = __builtin_amdgcn_readlane(m, j);
        bool less = (kj < key) || (kj == key && mj < m);   // stable: lower idx first
        rank += less ? 1 : 0;
    }
    if (lane < TSEL && rank < 2 * KOUT && (rank & 1) == 0) {  // dilation D=2: even ranks
        int k = rank >> 1;
        const float* xn = xyz + ((size_t)b * NPTS + n) * 3;
        const float* xm = xyz + ((size_t)b * NPTS + m) * 3;
        float xnx = xn[0], xny = xn[1], xnz = xn[2];
        float ox = xm[0], oy = xm[1], oz = xm[2];
        float rx = xnx - ox, ry = xny - oy, rz = xnz - oz;
        float dis = sqrtf(rx * rx + ry * ry + rz * rz);
        float* o = out + (((size_t)b * NPTS + n) * KOUT + k) * 10;
        o[0] = dis; o[1] = rx; o[2] = ry; o[3] = rz;
        o[4] = xnx; o[5] = xny; o[6] = xnz;
        o[7] = ox;  o[8] = oy;  o[9] = oz;
    }
}

// MFMA preselect, tile-specialized: per chunk, wave w computes ONE 16x16
// N-tile (cands 16w..16w+15 x all 16 block rows) via 2x mfma_f32_16x16x32_bf16,
// publishes it to slds, mid-chunk barrier, then every wave reads its 4 rows
// for its 64 cands. C layout (m89-verified): col=lane&15, row=(lane>>4)*4+reg.
// slds cand stride 80B: banks 20c mod 32 -> 2-way (free); 64B would be 8-way.
__global__ __launch_bounds__(256, 3) void knn_kernel(
    const float* __restrict__ xyz,
    const float* __restrict__ pts,
    const float* __restrict__ sqw,
    float* __restrict__ out) {

    __shared__ __align__(16) unsigned short ylds[2][CHUNK * (ROWB / 2)];  // 18.4 KB bf16 dbuf
    __shared__ __align__(16) float slds[4][16][20];                       //  5.0 KB S-tile exchange

    const int tid = threadIdx.x;
    const int lane = tid & 63;
    const int wave = tid >> 6;
    const int b = blockIdx.x >> 8;                  // 256 blocks per batch
    const int rowbase = (blockIdx.x & 255) << 4;    // 16 rows per block
    const int nw = __builtin_amdgcn_readfirstlane(rowbase + wave * RPW);
    const float* pb = pts + (size_t)b * NPTS * NC;
    const float* sqb = sqw + (size_t)b * NPTS;

    // A fragments (once per block): lane holds query row (lane&15), feats
    // (lane>>4)*8 + {0..7} (+32 for the K=32..63 fragment), packed bf16.
    s16x8 afrag0, afrag1;
    {
        const float* xrow = pb + (size_t)(rowbase + (lane & 15)) * NC + (lane >> 4) * 8;
        float4 xa0 = *(const float4*)(xrow);
        float4 xa1 = *(const float4*)(xrow + 4);
        float4 xb0 = *(const float4*)(xrow + 32);
        float4 xb1 = *(const float4*)(xrow + 36);
        u32x4 a0p = { pkbf(xa0.x, xa0.y), pkbf(xa0.z, xa0.w),
                      pkbf(xa1.x, xa1.y), pkbf(xa1.z, xa1.w) };
        u32x4 a1p = { pkbf(xb0.x, xb0.y), pkbf(xb0.z, xb0.w),
                      pkbf(xb1.x, xb1.y), pkbf(xb1.z, xb1.w) };
        afrag0 = __builtin_bit_cast(s16x8, a0p);
        afrag1 = __builtin_bit_cast(s16x8, a1p);
    }

    const float sqn0 = sqb[nw + 0];    // uniform -> scalar loads
    const float sqn1 = sqb[nw + 1];
    const float sqn2 = sqb[nw + 2];
    const float sqn3 = sqb[nw + 3];

    uint32_t list0 = 0xFFFFFFFFu, list1 = 0xFFFFFFFFu;
    uint32_t list2 = 0xFFFFFFFFu, list3 = 0xFFFFFFFFu;

    const float4* gsrc = (const float4*)pb;
    float4 pf[4];
#pragma unroll
    for (int j = 0; j < 4; ++j) pf[j] = gsrc[tid + 256 * j];   // prefetch chunk 0

    // stage chunk 0 into buffer 0 (fp32 -> bf16 pack)
#pragma unroll
    for (int j = 0; j < 4; ++j) {
        int s = tid + 256 * j;
        u32x2 w2 = { pkbf(pf[j].x, pf[j].y), pkbf(pf[j].z, pf[j].w) };
        *(u32x2*)((char*)ylds[0] + (s >> 4) * ROWB + (s & 15) * 8) = w2;
    }
    __syncthreads();

    for (int c = 0; c < NCHUNK; ++c) {
        const int cb = c & 1;
        if (c + 1 < NCHUNK) {
#pragma unroll
            for (int j = 0; j < 4; ++j)
                pf[j] = gsrc[(size_t)(c + 1) * (CHUNK * 16) + tid + 256 * j];
        }
        {
            const int m = c * CHUNK + lane;
            float sqm = sqb[m];
            // this wave's tile: cands 16*wave..16*wave+15, all 16 block rows
            const char* bp = (const char*)ylds[cb] + wave * (16 * ROWB)
                           + (lane & 15) * ROWB + (lane >> 4) * 16;
            s16x8 b0 = *(const s16x8*)(bp);        // K 0..31 fragment
            s16x8 b1 = *(const s16x8*)(bp + 64);   // K 32..63 fragment
            f32x4v cc = {0.f, 0.f, 0.f, 0.f};
            cc = __builtin_amdgcn_mfma_f32_16x16x32_bf16(afrag0, b0, cc, 0, 0, 0);
            cc = __builtin_amdgcn_mfma_f32_16x16x32_bf16(afrag1, b1, cc, 0, 0, 0);
            // publish: [tile][cand][rows 4*(lane>>4)..+3]
            *(f32x4v*)&slds[wave][lane & 15][(lane >> 4) * 4] = cc;
            __syncthreads();   // all tiles published
            // lane's cand lives in tile lane>>4, col lane&15; rows 4*wave..+3
            f32x4v ip = *(const f32x4v*)&slds[lane >> 4][lane & 15][wave * 4];
            float t0 = fmaxf(fmaf(-2.f, ip.x, sqn0 + sqm), 0.f);
            float t1 = fmaxf(fmaf(-2.f, ip.y, sqn1 + sqm), 0.f);
            float t2 = fmaxf(fmaf(-2.f, ip.z, sqn2 + sqm), 0.f);
            float t3 = fmaxf(fmaf(-2.f, ip.w, sqn3 + sqm), 0.f);
            uint32_t c0 = (__float_as_uint(t0) & KEYMASK) | (unsigned)m;
            uint32_t c1 = (__float_as_uint(t1) & KEYMASK) | (unsigned)m;
            uint32_t c2 = (__float_as_uint(t2) & KEYMASK) | (unsigned)m;
            uint32_t c3 = (__float_as_uint(t3) & KEYMASK) | (unsigned)m;
            stream_insert(list0, c0, lane);
            stream_insert(list1, c1, lane);
            stream_insert(list2, c2, lane);
            stream_insert(list3, c3, lane);
        }
        if (c + 1 < NCHUNK) {
#pragma unroll
            for (int j = 0; j < 4; ++j) {
                int s = tid + 256 * j;
                u32x2 w2 = { pkbf(pf[j].x, pf[j].y), pkbf(pf[j].z, pf[j].w) };
                *(u32x2*)((char*)ylds[cb ^ 1] + (s >> 4) * ROWB + (s & 15) * 8) = w2;
            }
        }
        __syncthreads();   // next buffer staged; slds consumed by all waves
    }

    epilogue(list0, nw + 0, b, lane, pb, sqb, sqn0, xyz, out);
    epilogue(list1, nw + 1, b, lane, pb, sqb, sqn1, xyz, out);
    epilogue(list2, nw + 2, b, lane, pb, sqb, sqn2, xyz, out);
    epilogue(list3, nw + 3, b, lane, pb, sqb, sqn3, xyz, out);
}

extern "C" void kernel_launch(void* const* d_in, const int* in_sizes, int n_in,
                              void* d_out, int out_size, void* d_ws, size_t ws_size,
                              hipStream_t stream) {
    const float* xyz = (const float*)d_in[0];   // [8,4096,3]
    const float* pts = (const float*)d_in[1];   // [8,4096,64]
    float* sqw = (float*)d_ws;                  // 32768 floats = 128 KB scratch
    float* out = (float*)d_out;                 // [8,4096,16,10]

    sq_kernel<<<(NB * NPTS) / 256, 256, 0, stream>>>(pts, sqw);
    knn_kernel<<<(NB * NPTS) / RPB, 256, 0, stream>>>(xyz, pts, sqw, out);
}

// Round 15
// 398.762 us; speedup vs baseline: 5.7138x; 1.0005x over previous
//
#include <hip/hip_runtime.h>
#include <stdint.h>

typedef unsigned long long u64;
typedef __attribute__((ext_vector_type(8))) short s16x8;     // 8 bf16 = 4 VGPRs
typedef __attribute__((ext_vector_type(4))) float f32x4v;
typedef __attribute__((ext_vector_type(4))) unsigned int u32x4;
typedef __attribute__((ext_vector_type(2))) unsigned int u32x2;

#define NB 8
#define NPTS 4096
#define NC 64
#define KOUT 16
#define TSEL 48          // preselect size; bf16 key err ~0.1 << rank-32->48 gap ~2.9
#define CHUNK 64         // candidate rows per staged chunk
#define NCHUNK (NPTS / CHUNK)
#define IDXBITS 0xFFFu
#define KEYMASK 0xFFFFF000u
#define RPW 8            // rows per wave (amortizes all per-chunk fixed costs)
#define RPB 32           // rows per block (4 waves)
#define ROWB 144         // bytes per Y LDS row: 64 bf16 (128B) + 16B pad (2-way banks = free)

// sq[p]: 8 accumulator chains over stride-8 (numpy pairwise-8 == XLA W8 reduce
// chains), separate mul/add roundings, combined ((r0+r1)+(r2+r3))+((r4+r5)+(r6+r7)).
__global__ __launch_bounds__(256) void sq_kernel(const float* __restrict__ pts,
                                                 float* __restrict__ sqw) {
    int p = blockIdx.x * 256 + threadIdx.x;
    const float* r = pts + (size_t)p * NC;
    float acc[8];
#pragma unroll
    for (int j = 0; j < 8; ++j) acc[j] = __fmul_rn(r[j], r[j]);
#pragma unroll
    for (int i = 8; i < 64; i += 8)
#pragma unroll
        for (int j = 0; j < 8; ++j)
            acc[j] = __fadd_rn(acc[j], __fmul_rn(r[i + j], r[i + j]));
    float s01 = __fadd_rn(acc[0], acc[1]);
    float s23 = __fadd_rn(acc[2], acc[3]);
    float s45 = __fadd_rn(acc[4], acc[5]);
    float s67 = __fadd_rn(acc[6], acc[7]);
    sqw[p] = __fadd_rn(__fadd_rn(s01, s23), __fadd_rn(s45, s67));
}

// pack two fp32 -> u32 of two bf16 (truncation; pure bit-move, b in high half)
static __device__ __forceinline__ uint32_t pkbf(float a, float b) {
#if __has_builtin(__builtin_amdgcn_perm)
    return __builtin_amdgcn_perm(__float_as_uint(b), __float_as_uint(a), 0x07060302);
#else
    return (__float_as_uint(b) & 0xFFFF0000u) | (__float_as_uint(a) >> 16);
#endif
}

// Maintain an ascending sorted 64-list, one u32 per lane:
// (fp32 key bits truncated to 20 | 12-bit idx). Key >= 0 so uint order == key
// order. Threshold = lane 47 (48th smallest). Wave-parallel shift insert.
__device__ __forceinline__ void stream_insert(uint32_t& list, uint32_t cand, int lane) {
    uint32_t thr = (uint32_t)__builtin_amdgcn_readlane((int)list, 47);
    u64 mask = __ballot(cand < thr);
    while (mask) {
        int src = __ffsll((long long)mask) - 1;
        uint32_t v = (uint32_t)__builtin_amdgcn_readlane((int)cand, src);  // uniform src
        int pos = __popcll(__ballot(list < v));
        uint32_t up = __shfl_up(list, 1);
        list = (lane < pos) ? list : ((lane == pos) ? v : up);
        mask &= (mask - 1);
    }
}

// Re-rank the 48 preselected candidates by the emulated reference key:
// key = fl(fl(sq_n - fl(2*inner)) + sq_m), inner = ONE sequential FMA chain
// over k = 0..63 ascending (XLA:CPU dot_general / Eigen gebp order).
__device__ __forceinline__ void epilogue(uint32_t list, int n, int b, int lane,
                                         const float* __restrict__ pb,
                                         const float* __restrict__ sqb,
                                         float sqn,
                                         const float* __restrict__ xyz,
                                         float* __restrict__ out) {
    int m = (int)(list & IDXBITS);        // every lane holds a real index after chunk 0
    const float4* xr = (const float4*)(pb + (size_t)n * NC);
    const float4* yr = (const float4*)(pb + (size_t)m * NC);
    float acc = 0.f;
#pragma unroll
    for (int i = 0; i < 16; ++i) {
        float4 xv = xr[i];
        float4 yv = yr[i];
        acc = __fmaf_rn(xv.x, yv.x, acc);
        acc = __fmaf_rn(xv.y, yv.y, acc);
        acc = __fmaf_rn(xv.z, yv.z, acc);
        acc = __fmaf_rn(xv.w, yv.w, acc);
    }
    float key = __fadd_rn(__fsub_rn(sqn, __fmul_rn(2.0f, acc)), sqb[m]);

    int rank = 0;
    uint32_t kb = __float_as_uint(key);
#pragma unroll 1
    for (int j = 0; j < TSEL; ++j) {
        float kj = __uint_as_float(
            (uint32_t)__builtin_amdgcn_readlane((int)kb, j));
        int mj = __builtin_amdgcn_readlane(m, j);
        bool less = (kj < key) || (kj == key && mj < m);   // stable: lower idx first
        rank += less ? 1 : 0;
    }
    if (lane < TSEL && rank < 2 * KOUT && (rank & 1) == 0) {  // dilation D=2: even ranks
        int k = rank >> 1;
        const float* xn = xyz + ((size_t)b * NPTS + n) * 3;
        const float* xm = xyz + ((size_t)b * NPTS + m) * 3;
        float xnx = xn[0], xny = xn[1], xnz = xn[2];
        float ox = xm[0], oy = xm[1], oz = xm[2];
        float rx = xnx - ox, ry = xny - oy, rz = xnz - oz;
        float dis = sqrtf(rx * rx + ry * ry + rz * rz);
        float* o = out + (((size_t)b * NPTS + n) * KOUT + k) * 10;
        o[0] = dis; o[1] = rx; o[2] = ry; o[3] = rz;
        o[4] = xnx; o[5] = xny; o[6] = xnz;
        o[7] = ox;  o[8] = oy;  o[9] = oz;
    }
}

// MFMA preselect, tile-specialized, 32 rows/block: per chunk, wave w computes
// cands 16w..16w+15 x all 32 block rows (2 stacked 16x16 tiles, 4 MFMA from
// 2 shared B-frag reads), publishes to slds, barrier, every wave reads its
// 8 rows for its 64 cands. C layout (m89): col=lane&15, row=(lane>>4)*4+reg.
// slds cand stride 144B -> banks 4c mod 32: 2-way on publish & consume (free).
__global__ __launch_bounds__(256, 3) void knn_kernel(
    const float* __restrict__ xyz,
    const float* __restrict__ pts,
    const float* __restrict__ sqw,
    float* __restrict__ out) {

    __shared__ __align__(16) unsigned short ylds[2][CHUNK * (ROWB / 2)];  // 18.4 KB bf16 dbuf
    __shared__ __align__(16) float slds[4][16][36];                       //  9.2 KB S-tile exchange

    const int tid = threadIdx.x;
    const int lane = tid & 63;
    const int wave = tid >> 6;
    const int b = blockIdx.x >> 7;                  // 128 blocks per batch
    const int rowbase = (blockIdx.x & 127) << 5;    // 32 rows per block
    const int nw = __builtin_amdgcn_readfirstlane(rowbase + wave * RPW);
    const float* pb = pts + (size_t)b * NPTS * NC;
    const float* sqb = sqw + (size_t)b * NPTS;

    // A fragments (once per block): rows rowbase..+15 (pair A) and ..16..+31
    // (pair B); lane holds row (lane&15), feats (lane>>4)*8+{0..7} (+32).
    s16x8 aA0, aA1, aB0, aB1;
    {
        const float* xrowA = pb + (size_t)(rowbase + (lane & 15)) * NC + (lane >> 4) * 8;
        const float* xrowB = xrowA + 16 * NC;
#pragma unroll
        for (int h = 0; h < 2; ++h) {
            const float* xr = h ? xrowB : xrowA;
            float4 xa0 = *(const float4*)(xr);
            float4 xa1 = *(const float4*)(xr + 4);
            float4 xb0 = *(const float4*)(xr + 32);
            float4 xb1 = *(const float4*)(xr + 36);
            u32x4 p0 = { pkbf(xa0.x, xa0.y), pkbf(xa0.z, xa0.w),
                         pkbf(xa1.x, xa1.y), pkbf(xa1.z, xa1.w) };
            u32x4 p1 = { pkbf(xb0.x, xb0.y), pkbf(xb0.z, xb0.w),
                         pkbf(xb1.x, xb1.y), pkbf(xb1.z, xb1.w) };
            if (h == 0) { aA0 = __builtin_bit_cast(s16x8, p0); aA1 = __builtin_bit_cast(s16x8, p1); }
            else        { aB0 = __builtin_bit_cast(s16x8, p0); aB1 = __builtin_bit_cast(s16x8, p1); }
        }
    }

    float sqn[RPW];
#pragma unroll
    for (int r = 0; r < RPW; ++r) sqn[r] = sqb[nw + r];   // uniform -> scalar loads

    uint32_t list[RPW];
#pragma unroll
    for (int r = 0; r < RPW; ++r) list[r] = 0xFFFFFFFFu;

    const float4* gsrc = (const float4*)pb;
    float4 pf[4];
#pragma unroll
    for (int j = 0; j < 4; ++j) pf[j] = gsrc[tid + 256 * j];   // prefetch chunk 0

    // stage chunk 0 into buffer 0 (fp32 -> bf16 pack)
#pragma unroll
    for (int j = 0; j < 4; ++j) {
        int s = tid + 256 * j;
        u32x2 w2 = { pkbf(pf[j].x, pf[j].y), pkbf(pf[j].z, pf[j].w) };
        *(u32x2*)((char*)ylds[0] + (s >> 4) * ROWB + (s & 15) * 8) = w2;
    }
    __syncthreads();

    for (int c = 0; c < NCHUNK; ++c) {
        const int cb = c & 1;
        if (c + 1 < NCHUNK) {
#pragma unroll
            for (int j = 0; j < 4; ++j)
                pf[j] = gsrc[(size_t)(c + 1) * (CHUNK * 16) + tid + 256 * j];
        }
        {
            const int m = c * CHUNK + lane;
            float sqm = sqb[m];
            // this wave's tile pair: cands 16*wave..16*wave+15, rows 0..31
            const char* bp = (const char*)ylds[cb] + wave * (16 * ROWB)
                           + (lane & 15) * ROWB + (lane >> 4) * 16;
            s16x8 b0 = *(const s16x8*)(bp);        // K 0..31 fragment
            s16x8 b1 = *(const s16x8*)(bp + 64);   // K 32..63 fragment
            f32x4v cc0 = {0.f, 0.f, 0.f, 0.f};
            f32x4v cc1 = {0.f, 0.f, 0.f, 0.f};
            cc0 = __builtin_amdgcn_mfma_f32_16x16x32_bf16(aA0, b0, cc0, 0, 0, 0);
            cc0 = __builtin_amdgcn_mfma_f32_16x16x32_bf16(aA1, b1, cc0, 0, 0, 0);
            cc1 = __builtin_amdgcn_mfma_f32_16x16x32_bf16(aB0, b0, cc1, 0, 0, 0);
            cc1 = __builtin_amdgcn_mfma_f32_16x16x32_bf16(aB1, b1, cc1, 0, 0, 0);
            // publish: [tile][cand][rows]: cc0 -> 4*(lane>>4).., cc1 -> +16
            *(f32x4v*)&slds[wave][lane & 15][(lane >> 4) * 4] = cc0;
            *(f32x4v*)&slds[wave][lane & 15][16 + (lane >> 4) * 4] = cc1;
            __syncthreads();   // all tiles published
            // lane's cand: tile lane>>4, col lane&15; this wave's rows 8w..8w+7
            f32x4v ipa = *(const f32x4v*)&slds[lane >> 4][lane & 15][wave * 8];
            f32x4v ipb = *(const f32x4v*)&slds[lane >> 4][lane & 15][wave * 8 + 4];
            float ip[RPW] = { ipa.x, ipa.y, ipa.z, ipa.w, ipb.x, ipb.y, ipb.z, ipb.w };
#pragma unroll
            for (int r = 0; r < RPW; ++r) {
                float t = fmaxf(fmaf(-2.f, ip[r], sqn[r] + sqm), 0.f);
                uint32_t cd = (__float_as_uint(t) & KEYMASK) | (unsigned)m;
                stream_insert(list[r], cd, lane);
            }
        }
        if (c + 1 < NCHUNK) {
#pragma unroll
            for (int j = 0; j < 4; ++j) {
                int s = tid + 256 * j;
                u32x2 w2 = { pkbf(pf[j].x, pf[j].y), pkbf(pf[j].z, pf[j].w) };
                *(u32x2*)((char*)ylds[cb ^ 1] + (s >> 4) * ROWB + (s & 15) * 8) = w2;
            }
        }
        __syncthreads();   // next buffer staged; slds consumed by all waves
    }

#pragma unroll 1
    for (int r = 0; r < RPW; ++r)
        epilogue(list[r], nw + r, b, lane, pb, sqb, sqn[r], xyz, out);
}

extern "C" void kernel_launch(void* const* d_in, const int* in_sizes, int n_in,
                              void* d_out, int out_size, void* d_ws, size_t ws_size,
                              hipStream_t stream) {
    const float* xyz = (const float*)d_in[0];   // [8,4096,3]
    const float* pts = (const float*)d_in[1];   // [8,4096,64]
    float* sqw = (float*)d_ws;                  // 32768 floats = 128 KB scratch
    float* out = (float*)d_out;                 // [8,4096,16,10]

    sq_kernel<<<(NB * NPTS) / 256, 256, 0, stream>>>(pts, sqw);
    knn_kernel<<<(NB * NPTS) / RPB, 256, 0, stream>>>(xyz, pts, sqw, out);
}

// Round 16
// 381.616 us; speedup vs baseline: 5.9705x; 1.0449x over previous
//
#include <hip/hip_runtime.h>
#include <stdint.h>

typedef unsigned long long u64;
typedef __attribute__((ext_vector_type(8))) short s16x8;     // 8 bf16 = 4 VGPRs
typedef __attribute__((ext_vector_type(4))) float f32x4v;
typedef __attribute__((ext_vector_type(4))) unsigned int u32x4;
typedef __attribute__((ext_vector_type(2))) unsigned int u32x2;

#define NB 8
#define NPTS 4096
#define NC 64
#define KOUT 16
#define TSEL 40          // preselect size; combined key err sigma ~0.04 << 8-rank gap ~1.5 (30+ sigma)
#define CHUNK 64         // candidate rows per staged chunk
#define NCHUNK (NPTS / CHUNK)
#define IDXBITS 0xFFFu
#define KEYMASK 0xFFFFF000u
#define RPW 8            // rows per wave
#define RPB 32           // rows per block (4 waves)
#define ROWB 144         // bytes per Y LDS row: 64 bf16 (128B) + 16B pad (2-way banks = free)

// sq[p]: 8 accumulator chains over stride-8 (numpy pairwise-8 == XLA W8 reduce
// chains), separate mul/add roundings, combined ((r0+r1)+(r2+r3))+((r4+r5)+(r6+r7)).
__global__ __launch_bounds__(256) void sq_kernel(const float* __restrict__ pts,
                                                 float* __restrict__ sqw) {
    int p = blockIdx.x * 256 + threadIdx.x;
    const float* r = pts + (size_t)p * NC;
    float acc[8];
#pragma unroll
    for (int j = 0; j < 8; ++j) acc[j] = __fmul_rn(r[j], r[j]);
#pragma unroll
    for (int i = 8; i < 64; i += 8)
#pragma unroll
        for (int j = 0; j < 8; ++j)
            acc[j] = __fadd_rn(acc[j], __fmul_rn(r[i + j], r[i + j]));
    float s01 = __fadd_rn(acc[0], acc[1]);
    float s23 = __fadd_rn(acc[2], acc[3]);
    float s45 = __fadd_rn(acc[4], acc[5]);
    float s67 = __fadd_rn(acc[6], acc[7]);
    sqw[p] = __fadd_rn(__fadd_rn(s01, s23), __fadd_rn(s45, s67));
}

// pack two fp32 -> u32 of two bf16 (truncation; pure bit-move, b in high half)
static __device__ __forceinline__ uint32_t pkbf(float a, float b) {
#if __has_builtin(__builtin_amdgcn_perm)
    return __builtin_amdgcn_perm(__float_as_uint(b), __float_as_uint(a), 0x07060302);
#else
    return (__float_as_uint(b) & 0xFFFF0000u) | (__float_as_uint(a) >> 16);
#endif
}

// Maintain an ascending sorted 64-list, one u32 per lane:
// (fp32 key bits truncated to 20 | 12-bit idx). Key >= 0 so uint order == key
// order. Threshold = lane TSEL-1 (40th smallest). Wave-parallel shift insert.
__device__ __forceinline__ void stream_insert(uint32_t& list, uint32_t cand, int lane) {
    uint32_t thr = (uint32_t)__builtin_amdgcn_readlane((int)list, TSEL - 1);
    u64 mask = __ballot(cand < thr);
    while (mask) {
        int src = __ffsll((long long)mask) - 1;
        uint32_t v = (uint32_t)__builtin_amdgcn_readlane((int)cand, src);  // uniform src
        int pos = __popcll(__ballot(list < v));
        uint32_t up = __shfl_up(list, 1);
        list = (lane < pos) ? list : ((lane == pos) ? v : up);
        mask &= (mask - 1);
    }
}

// Re-rank the TSEL preselected candidates by the emulated reference key:
// key = fl(fl(sq_n - fl(2*inner)) + sq_m), inner = ONE sequential FMA chain
// over k = 0..63 ascending (XLA:CPU dot_general / Eigen gebp order).
__device__ __forceinline__ void epilogue(uint32_t list, int n, int b, int lane,
                                         const float* __restrict__ pb,
                                         const float* __restrict__ sqb,
                                         float sqn,
                                         const float* __restrict__ xyz,
                                         float* __restrict__ out) {
    int m = (int)(list & IDXBITS);        // every lane holds a real index after chunk 0
    const float4* xr = (const float4*)(pb + (size_t)n * NC);
    const float4* yr = (const float4*)(pb + (size_t)m * NC);
    float acc = 0.f;
#pragma unroll
    for (int i = 0; i < 16; ++i) {
        float4 xv = xr[i];
        float4 yv = yr[i];
        acc = __fmaf_rn(xv.x, yv.x, acc);
        acc = __fmaf_rn(xv.y, yv.y, acc);
        acc = __fmaf_rn(xv.z, yv.z, acc);
        acc = __fmaf_rn(xv.w, yv.w, acc);
    }
    float key = __fadd_rn(__fsub_rn(sqn, __fmul_rn(2.0f, acc)), sqb[m]);

    int rank = 0;
    uint32_t kb = __float_as_uint(key);
#pragma unroll 1
    for (int j = 0; j < TSEL; ++j) {
        float kj = __uint_as_float(
            (uint32_t)__builtin_amdgcn_readlane((int)kb, j));
        int mj = __builtin_amdgcn_readlane(m, j);
        bool less = (kj < key) || (kj == key && mj < m);   // stable: lower idx first
        rank += less ? 1 : 0;
    }
    if (lane < TSEL && rank < 2 * KOUT && (rank & 1) == 0) {  // dilation D=2: even ranks
        int k = rank >> 1;
        const float* xn = xyz + ((size_t)b * NPTS + n) * 3;
        const float* xm = xyz + ((size_t)b * NPTS + m) * 3;
        float xnx = xn[0], xny = xn[1], xnz = xn[2];
        float ox = xm[0], oy = xm[1], oz = xm[2];
        float rx = xnx - ox, ry = xny - oy, rz = xnz - oz;
        float dis = sqrtf(rx * rx + ry * ry + rz * rz);
        float* o = out + (((size_t)b * NPTS + n) * KOUT + k) * 10;
        o[0] = dis; o[1] = rx; o[2] = ry; o[3] = rz;
        o[4] = xnx; o[5] = xny; o[6] = xnz;
        o[7] = ox;  o[8] = oy;  o[9] = oz;
    }
}

// MFMA preselect, tile-specialized, 32 rows/block, ONE barrier per chunk:
// slds is double-buffered so publish(c+1) never races consume(c). Order per
// chunk: MFMA (reads ylds[cb]) -> publish slds[sb] -> stage ylds[cb^1] ->
// BARRIER -> consume slds[sb] + inserts. All cross-wave dependencies are
// separated by exactly one barrier (race audit in journal).
// C layout (m89): col=lane&15, row=(lane>>4)*4+reg.
__global__ __launch_bounds__(256, 3) void knn_kernel(
    const float* __restrict__ xyz,
    const float* __restrict__ pts,
    const float* __restrict__ sqw,
    float* __restrict__ out) {

    __shared__ __align__(16) unsigned short ylds[2][CHUNK * (ROWB / 2)];  // 18.4 KB bf16 dbuf
    __shared__ __align__(16) float slds[2][4][16][36];                    // 18.4 KB S-tile dbuf

    const int tid = threadIdx.x;
    const int lane = tid & 63;
    const int wave = tid >> 6;
    const int b = blockIdx.x >> 7;                  // 128 blocks per batch
    const int rowbase = (blockIdx.x & 127) << 5;    // 32 rows per block
    const int nw = __builtin_amdgcn_readfirstlane(rowbase + wave * RPW);
    const float* pb = pts + (size_t)b * NPTS * NC;
    const float* sqb = sqw + (size_t)b * NPTS;

    // A fragments (once per block): rows rowbase..+15 (pair A) and ..16..+31
    // (pair B); lane holds row (lane&15), feats (lane>>4)*8+{0..7} (+32).
    s16x8 aA0, aA1, aB0, aB1;
    {
        const float* xrowA = pb + (size_t)(rowbase + (lane & 15)) * NC + (lane >> 4) * 8;
        const float* xrowB = xrowA + 16 * NC;
#pragma unroll
        for (int h = 0; h < 2; ++h) {
            const float* xr = h ? xrowB : xrowA;
            float4 xa0 = *(const float4*)(xr);
            float4 xa1 = *(const float4*)(xr + 4);
            float4 xb0 = *(const float4*)(xr + 32);
            float4 xb1 = *(const float4*)(xr + 36);
            u32x4 p0 = { pkbf(xa0.x, xa0.y), pkbf(xa0.z, xa0.w),
                         pkbf(xa1.x, xa1.y), pkbf(xa1.z, xa1.w) };
            u32x4 p1 = { pkbf(xb0.x, xb0.y), pkbf(xb0.z, xb0.w),
                         pkbf(xb1.x, xb1.y), pkbf(xb1.z, xb1.w) };
            if (h == 0) { aA0 = __builtin_bit_cast(s16x8, p0); aA1 = __builtin_bit_cast(s16x8, p1); }
            else        { aB0 = __builtin_bit_cast(s16x8, p0); aB1 = __builtin_bit_cast(s16x8, p1); }
        }
    }

    float sqn[RPW];
#pragma unroll
    for (int r = 0; r < RPW; ++r) sqn[r] = sqb[nw + r];   // uniform -> scalar loads

    uint32_t list[RPW];
#pragma unroll
    for (int r = 0; r < RPW; ++r) list[r] = 0xFFFFFFFFu;

    const float4* gsrc = (const float4*)pb;
    float4 pf[4];
#pragma unroll
    for (int j = 0; j < 4; ++j) pf[j] = gsrc[tid + 256 * j];   // prefetch chunk 0

    // stage chunk 0 into buffer 0 (fp32 -> bf16 pack)
#pragma unroll
    for (int j = 0; j < 4; ++j) {
        int s = tid + 256 * j;
        u32x2 w2 = { pkbf(pf[j].x, pf[j].y), pkbf(pf[j].z, pf[j].w) };
        *(u32x2*)((char*)ylds[0] + (s >> 4) * ROWB + (s & 15) * 8) = w2;
    }
    __syncthreads();

    for (int c = 0; c < NCHUNK; ++c) {
        const int cb = c & 1;
        if (c + 1 < NCHUNK) {
#pragma unroll
            for (int j = 0; j < 4; ++j)
                pf[j] = gsrc[(size_t)(c + 1) * (CHUNK * 16) + tid + 256 * j];
        }
        const int m = c * CHUNK + lane;
        float sqm = sqb[m];
        {
            // this wave's tile pair: cands 16*wave..16*wave+15, rows 0..31
            const char* bp = (const char*)ylds[cb] + wave * (16 * ROWB)
                           + (lane & 15) * ROWB + (lane >> 4) * 16;
            s16x8 b0 = *(const s16x8*)(bp);        // K 0..31 fragment
            s16x8 b1 = *(const s16x8*)(bp + 64);   // K 32..63 fragment
            f32x4v cc0 = {0.f, 0.f, 0.f, 0.f};
            f32x4v cc1 = {0.f, 0.f, 0.f, 0.f};
            cc0 = __builtin_amdgcn_mfma_f32_16x16x32_bf16(aA0, b0, cc0, 0, 0, 0);
            cc0 = __builtin_amdgcn_mfma_f32_16x16x32_bf16(aA1, b1, cc0, 0, 0, 0);
            cc1 = __builtin_amdgcn_mfma_f32_16x16x32_bf16(aB0, b0, cc1, 0, 0, 0);
            cc1 = __builtin_amdgcn_mfma_f32_16x16x32_bf16(aB1, b1, cc1, 0, 0, 0);
            // publish: [sb][tile][cand][rows]: cc0 -> 4*(lane>>4).., cc1 -> +16
            *(f32x4v*)&slds[cb][wave][lane & 15][(lane >> 4) * 4] = cc0;
            *(f32x4v*)&slds[cb][wave][lane & 15][16 + (lane >> 4) * 4] = cc1;
        }
        if (c + 1 < NCHUNK) {   // stage next chunk before the barrier
#pragma unroll
            for (int j = 0; j < 4; ++j) {
                int s = tid + 256 * j;
                u32x2 w2 = { pkbf(pf[j].x, pf[j].y), pkbf(pf[j].z, pf[j].w) };
                *(u32x2*)((char*)ylds[cb ^ 1] + (s >> 4) * ROWB + (s & 15) * 8) = w2;
            }
        }
        __syncthreads();   // tiles published AND next chunk staged
        {
            // lane's cand: tile lane>>4, col lane&15; this wave's rows 8w..8w+7
            f32x4v ipa = *(const f32x4v*)&slds[cb][lane >> 4][lane & 15][wave * 8];
            f32x4v ipb = *(const f32x4v*)&slds[cb][lane >> 4][lane & 15][wave * 8 + 4];
            float ip[RPW] = { ipa.x, ipa.y, ipa.z, ipa.w, ipb.x, ipb.y, ipb.z, ipb.w };
#pragma unroll
            for (int r = 0; r < RPW; ++r) {
                float t = fmaxf(fmaf(-2.f, ip[r], sqn[r] + sqm), 0.f);
                uint32_t cd = (__float_as_uint(t) & KEYMASK) | (unsigned)m;
                stream_insert(list[r], cd, lane);
            }
        }
    }

#pragma unroll 1
    for (int r = 0; r < RPW; ++r)
        epilogue(list[r], nw + r, b, lane, pb, sqb, sqn[r], xyz, out);
}

extern "C" void kernel_launch(void* const* d_in, const int* in_sizes, int n_in,
                              void* d_out, int out_size, void* d_ws, size_t ws_size,
                              hipStream_t stream) {
    const float* xyz = (const float*)d_in[0];   // [8,4096,3]
    const float* pts = (const float*)d_in[1];   // [8,4096,64]
    float* sqw = (float*)d_ws;                  // 32768 floats = 128 KB scratch
    float* out = (float*)d_out;                 // [8,4096,16,10]

    sq_kernel<<<(NB * NPTS) / 256, 256, 0, stream>>>(pts, sqw);
    knn_kernel<<<(NB * NPTS) / RPB, 256, 0, stream>>>(xyz, pts, sqw, out);
}

// Round 17
// 365.109 us; speedup vs baseline: 6.2404x; 1.0452x over previous
//
#include <hip/hip_runtime.h>
#include <stdint.h>

typedef unsigned long long u64;
typedef __attribute__((ext_vector_type(8))) short s16x8;     // 8 bf16 = 4 VGPRs
typedef __attribute__((ext_vector_type(4))) float f32x4v;
typedef __attribute__((ext_vector_type(4))) unsigned int u32x4;
typedef __attribute__((ext_vector_type(2))) unsigned int u32x2;

#define NB 8
#define NPTS 4096
#define NC 64
#define KOUT 16
#define TSEL 40          // preselect size; key err sigma ~0.04 << 8-rank gap ~1.5 (30+ sigma)
#define CHUNK 64         // candidate rows per staged chunk
#define NCHUNK (NPTS / CHUNK)
#define IDXBITS 0xFFFu
#define KEYMASK 0xFFFFF000u
#define RPW 4            // rows per wave (occupancy side of the RPW tradeoff)
#define RPB 16           // rows per block (4 waves)
#define ROWB 144         // bytes per Y LDS row: 64 bf16 (128B) + 16B pad (2-way banks = free)

// sq[p]: 8 accumulator chains over stride-8 (numpy pairwise-8 == XLA W8 reduce
// chains), separate mul/add roundings, combined ((r0+r1)+(r2+r3))+((r4+r5)+(r6+r7)).
__global__ __launch_bounds__(256) void sq_kernel(const float* __restrict__ pts,
                                                 float* __restrict__ sqw) {
    int p = blockIdx.x * 256 + threadIdx.x;
    const float* r = pts + (size_t)p * NC;
    float acc[8];
#pragma unroll
    for (int j = 0; j < 8; ++j) acc[j] = __fmul_rn(r[j], r[j]);
#pragma unroll
    for (int i = 8; i < 64; i += 8)
#pragma unroll
        for (int j = 0; j < 8; ++j)
            acc[j] = __fadd_rn(acc[j], __fmul_rn(r[i + j], r[i + j]));
    float s01 = __fadd_rn(acc[0], acc[1]);
    float s23 = __fadd_rn(acc[2], acc[3]);
    float s45 = __fadd_rn(acc[4], acc[5]);
    float s67 = __fadd_rn(acc[6], acc[7]);
    sqw[p] = __fadd_rn(__fadd_rn(s01, s23), __fadd_rn(s45, s67));
}

// pack two fp32 -> u32 of two bf16 (truncation; pure bit-move, b in high half)
static __device__ __forceinline__ uint32_t pkbf(float a, float b) {
#if __has_builtin(__builtin_amdgcn_perm)
    return __builtin_amdgcn_perm(__float_as_uint(b), __float_as_uint(a), 0x07060302);
#else
    return (__float_as_uint(b) & 0xFFFF0000u) | (__float_as_uint(a) >> 16);
#endif
}

// Maintain an ascending sorted 64-list, one u32 per lane:
// (fp32 key bits truncated to 20 | 12-bit idx). Key >= 0 so uint order == key
// order. Threshold = lane TSEL-1 (40th smallest). Wave-parallel shift insert.
__device__ __forceinline__ void stream_insert(uint32_t& list, uint32_t cand, int lane) {
    uint32_t thr = (uint32_t)__builtin_amdgcn_readlane((int)list, TSEL - 1);
    u64 mask = __ballot(cand < thr);
    while (mask) {
        int src = __ffsll((long long)mask) - 1;
        uint32_t v = (uint32_t)__builtin_amdgcn_readlane((int)cand, src);  // uniform src
        int pos = __popcll(__ballot(list < v));
        uint32_t up = __shfl_up(list, 1);
        list = (lane < pos) ? list : ((lane == pos) ? v : up);
        mask &= (mask - 1);
    }
}

// Re-rank the TSEL preselected candidates by the emulated reference key:
// key = fl(fl(sq_n - fl(2*inner)) + sq_m), inner = ONE sequential FMA chain
// over k = 0..63 ascending (XLA:CPU dot_general / Eigen gebp order).
__device__ __forceinline__ void epilogue(uint32_t list, int n, int b, int lane,
                                         const float* __restrict__ pb,
                                         const float* __restrict__ sqb,
                                         float sqn,
                                         const float* __restrict__ xyz,
                                         float* __restrict__ out) {
    int m = (int)(list & IDXBITS);        // every lane holds a real index after chunk 0
    const float4* xr = (const float4*)(pb + (size_t)n * NC);
    const float4* yr = (const float4*)(pb + (size_t)m * NC);
    float acc = 0.f;
#pragma unroll
    for (int i = 0; i < 16; ++i) {
        float4 xv = xr[i];
        float4 yv = yr[i];
        acc = __fmaf_rn(xv.x, yv.x, acc);
        acc = __fmaf_rn(xv.y, yv.y, acc);
        acc = __fmaf_rn(xv.z, yv.z, acc);
        acc = __fmaf_rn(xv.w, yv.w, acc);
    }
    float key = __fadd_rn(__fsub_rn(sqn, __fmul_rn(2.0f, acc)), sqb[m]);

    int rank = 0;
    uint32_t kb = __float_as_uint(key);
#pragma unroll 1
    for (int j = 0; j < TSEL; ++j) {
        float kj = __uint_as_float(
            (uint32_t)__builtin_amdgcn_readlane((int)kb, j));
        int mj = __builtin_amdgcn_readlane(m, j);
        bool less = (kj < key) || (kj == key && mj < m);   // stable: lower idx first
        rank += less ? 1 : 0;
    }
    if (lane < TSEL && rank < 2 * KOUT && (rank & 1) == 0) {  // dilation D=2: even ranks
        int k = rank >> 1;
        const float* xn = xyz + ((size_t)b * NPTS + n) * 3;
        const float* xm = xyz + ((size_t)b * NPTS + m) * 3;
        float xnx = xn[0], xny = xn[1], xnz = xn[2];
        float ox = xm[0], oy = xm[1], oz = xm[2];
        float rx = xnx - ox, ry = xny - oy, rz = xnz - oz;
        float dis = sqrtf(rx * rx + ry * ry + rz * rz);
        float* o = out + (((size_t)b * NPTS + n) * KOUT + k) * 10;
        o[0] = dis; o[1] = rx; o[2] = ry; o[3] = rz;
        o[4] = xnx; o[5] = xny; o[6] = xnz;
        o[7] = ox;  o[8] = oy;  o[9] = oz;
    }
}

// MFMA preselect, tile-specialized, 16 rows/block, ONE barrier per chunk,
// slds double-buffered (publish(c+1) never races consume(c)). Per chunk:
// MFMA (reads ylds[cb]) -> publish slds[cb] -> stage ylds[cb^1] -> BARRIER ->
// consume slds[cb] + inserts. LDS 28.7 KB -> 5 blocks/CU -> 62% occupancy cap.
// C layout (m89): col=lane&15, row=(lane>>4)*4+reg.
// slds cand stride 80B: banks 20c mod 32 -> 2-way publish & consume (free).
__global__ __launch_bounds__(256, 3) void knn_kernel(
    const float* __restrict__ xyz,
    const float* __restrict__ pts,
    const float* __restrict__ sqw,
    float* __restrict__ out) {

    __shared__ __align__(16) unsigned short ylds[2][CHUNK * (ROWB / 2)];  // 18.4 KB bf16 dbuf
    __shared__ __align__(16) float slds[2][4][16][20];                    // 10.0 KB S-tile dbuf

    const int tid = threadIdx.x;
    const int lane = tid & 63;
    const int wave = tid >> 6;
    const int b = blockIdx.x >> 8;                  // 256 blocks per batch
    const int rowbase = (blockIdx.x & 255) << 4;    // 16 rows per block
    const int nw = __builtin_amdgcn_readfirstlane(rowbase + wave * RPW);
    const float* pb = pts + (size_t)b * NPTS * NC;
    const float* sqb = sqw + (size_t)b * NPTS;

    // A fragments (once per block): lane holds query row (lane&15), feats
    // (lane>>4)*8 + {0..7} (+32 for the K=32..63 fragment), packed bf16.
    s16x8 afrag0, afrag1;
    {
        const float* xrow = pb + (size_t)(rowbase + (lane & 15)) * NC + (lane >> 4) * 8;
        float4 xa0 = *(const float4*)(xrow);
        float4 xa1 = *(const float4*)(xrow + 4);
        float4 xb0 = *(const float4*)(xrow + 32);
        float4 xb1 = *(const float4*)(xrow + 36);
        u32x4 a0p = { pkbf(xa0.x, xa0.y), pkbf(xa0.z, xa0.w),
                      pkbf(xa1.x, xa1.y), pkbf(xa1.z, xa1.w) };
        u32x4 a1p = { pkbf(xb0.x, xb0.y), pkbf(xb0.z, xb0.w),
                      pkbf(xb1.x, xb1.y), pkbf(xb1.z, xb1.w) };
        afrag0 = __builtin_bit_cast(s16x8, a0p);
        afrag1 = __builtin_bit_cast(s16x8, a1p);
    }

    float sqn[RPW];
#pragma unroll
    for (int r = 0; r < RPW; ++r) sqn[r] = sqb[nw + r];   // uniform -> scalar loads

    uint32_t list[RPW];
#pragma unroll
    for (int r = 0; r < RPW; ++r) list[r] = 0xFFFFFFFFu;

    const float4* gsrc = (const float4*)pb;
    float4 pf[4];
#pragma unroll
    for (int j = 0; j < 4; ++j) pf[j] = gsrc[tid + 256 * j];   // prefetch chunk 0

    // stage chunk 0 into buffer 0 (fp32 -> bf16 pack)
#pragma unroll
    for (int j = 0; j < 4; ++j) {
        int s = tid + 256 * j;
        u32x2 w2 = { pkbf(pf[j].x, pf[j].y), pkbf(pf[j].z, pf[j].w) };
        *(u32x2*)((char*)ylds[0] + (s >> 4) * ROWB + (s & 15) * 8) = w2;
    }
    __syncthreads();

    for (int c = 0; c < NCHUNK; ++c) {
        const int cb = c & 1;
        if (c + 1 < NCHUNK) {
#pragma unroll
            for (int j = 0; j < 4; ++j)
                pf[j] = gsrc[(size_t)(c + 1) * (CHUNK * 16) + tid + 256 * j];
        }
        const int m = c * CHUNK + lane;
        float sqm = sqb[m];
        {
            // this wave's tile: cands 16*wave..16*wave+15, all 16 block rows
            const char* bp = (const char*)ylds[cb] + wave * (16 * ROWB)
                           + (lane & 15) * ROWB + (lane >> 4) * 16;
            s16x8 b0 = *(const s16x8*)(bp);        // K 0..31 fragment
            s16x8 b1 = *(const s16x8*)(bp + 64);   // K 32..63 fragment
            f32x4v cc = {0.f, 0.f, 0.f, 0.f};
            cc = __builtin_amdgcn_mfma_f32_16x16x32_bf16(afrag0, b0, cc, 0, 0, 0);
            cc = __builtin_amdgcn_mfma_f32_16x16x32_bf16(afrag1, b1, cc, 0, 0, 0);
            // publish: [cb][tile][cand][rows 4*(lane>>4)..+3]
            *(f32x4v*)&slds[cb][wave][lane & 15][(lane >> 4) * 4] = cc;
        }
        if (c + 1 < NCHUNK) {   // stage next chunk before the barrier
#pragma unroll
            for (int j = 0; j < 4; ++j) {
                int s = tid + 256 * j;
                u32x2 w2 = { pkbf(pf[j].x, pf[j].y), pkbf(pf[j].z, pf[j].w) };
                *(u32x2*)((char*)ylds[cb ^ 1] + (s >> 4) * ROWB + (s & 15) * 8) = w2;
            }
        }
        __syncthreads();   // tiles published AND next chunk staged
        {
            // lane's cand: tile lane>>4, col lane&15; this wave's rows 4w..4w+3
            f32x4v ip = *(const f32x4v*)&slds[cb][lane >> 4][lane & 15][wave * 4];
            float ipr[RPW] = { ip.x, ip.y, ip.z, ip.w };
#pragma unroll
            for (int r = 0; r < RPW; ++r) {
                float t = fmaxf(fmaf(-2.f, ipr[r], sqn[r] + sqm), 0.f);
                uint32_t cd = (__float_as_uint(t) & KEYMASK) | (unsigned)m;
                stream_insert(list[r], cd, lane);
            }
        }
    }

#pragma unroll 1
    for (int r = 0; r < RPW; ++r)
        epilogue(list[r], nw + r, b, lane, pb, sqb, sqn[r], xyz, out);
}

extern "C" void kernel_launch(void* const* d_in, const int* in_sizes, int n_in,
                              void* d_out, int out_size, void* d_ws, size_t ws_size,
                              hipStream_t stream) {
    const float* xyz = (const float*)d_in[0];   // [8,4096,3]
    const float* pts = (const float*)d_in[1];   // [8,4096,64]
    float* sqw = (float*)d_ws;                  // 32768 floats = 128 KB scratch
    float* out = (float*)d_out;                 // [8,4096,16,10]

    sq_kernel<<<(NB * NPTS) / 256, 256, 0, stream>>>(pts, sqw);
    knn_kernel<<<(NB * NPTS) / RPB, 256, 0, stream>>>(xyz, pts, sqw, out);
}